// Round 6
// baseline (895.440 us; speedup 1.0000x reference)
//
#include <hip/hip_runtime.h>
#include <math.h>

#define NGRAPH 1000
#define NBK_MAX 400       // buckets of 512 nodes: ceil(200000/512)=391
#define PART_BLOCKS 256

typedef unsigned short ushort_t;
typedef __attribute__((ext_vector_type(8))) short short8;     // 8 bf16 (4 VGPRs)
typedef __attribute__((ext_vector_type(8))) _Float16 half8;   // 8 fp16 (4 VGPRs)
typedef __attribute__((ext_vector_type(4))) float floatx4;    // MFMA accumulator

static __device__ inline ushort_t f2bf(float f) {
  unsigned u = __float_as_uint(f);
  u = (u + 0x7fffu + ((u >> 16) & 1u)) >> 16;  // RNE
  return (ushort_t)u;
}
static __device__ inline ushort_t f2h_bits(float f) {
  return __builtin_bit_cast(ushort_t, (_Float16)f);  // RNE
}
static __device__ inline float h2f_bits(ushort_t u) {
  return (float)__builtin_bit_cast(_Float16, u);
}

// ---------------- Bucketed, atomic-free CSR build (BOTH sides batched) ----------------
// Buckets are 512 nodes (shift 9). ebuf entries packed to 4B:
// (src << 9) | (dst & 511)  -- src < 2^18, fits 27 bits.  blockIdx.y = side.

__global__ __launch_bounds__(1024) void bucket_hist2(const int* __restrict__ dst0,
                                                     const int* __restrict__ dst1, int E,
                                                     int chunk, int* __restrict__ hist, int nbk) {
  const int side = blockIdx.y;
  const int* __restrict__ dst = side ? dst1 : dst0;
  __shared__ int lh[NBK_MAX];
  for (int i = threadIdx.x; i < nbk; i += 1024) lh[i] = 0;
  __syncthreads();
  const int e0 = blockIdx.x * chunk;
  const int e1 = min(E, e0 + chunk);
  for (int e = e0 + threadIdx.x; e < e1; e += 1024) atomicAdd(&lh[dst[e] >> 9], 1);
  __syncthreads();
  int* row = hist + ((size_t)side * PART_BLOCKS + blockIdx.x) * nbk;
  for (int i = threadIdx.x; i < nbk; i += 1024) row[i] = lh[i];
}

// Parallel column scan: one block per (bucket, side), 256 threads = PART_BLOCKS.
__global__ __launch_bounds__(PART_BLOCKS) void colscan_par2(int* __restrict__ hist, int nbk,
                                                            int* __restrict__ totals) {
  __shared__ int s[PART_BLOCKS];
  const int side = blockIdx.y;
  int* __restrict__ hist_s = hist + (size_t)side * PART_BLOCKS * nbk;
  int* __restrict__ totals_s = totals + side * nbk;
  const int b = blockIdx.x;   // bucket
  const int t = threadIdx.x;  // partition block
  s[t] = hist_s[(size_t)t * nbk + b];
  __syncthreads();
  for (int off = 1; off < PART_BLOCKS; off <<= 1) {
    int u = (t >= off) ? s[t - off] : 0;
    __syncthreads();
    s[t] += u;
    __syncthreads();
  }
  const int exc = (t == 0) ? 0 : s[t - 1];
  hist_s[(size_t)t * nbk + b] = exc;
  if (t == PART_BLOCKS - 1) totals_s[b] = s[PART_BLOCKS - 1];
}

__global__ __launch_bounds__(1024) void scan_small2(const int* __restrict__ in, int n,
                                                    int* __restrict__ out) {
  __shared__ int s[2048];
  const int side = blockIdx.x;
  const int* __restrict__ in_s = in + side * n;
  int* __restrict__ out_s = out + side * (n + 1);
  const int t = threadIdx.x;
  s[t] = (t < n) ? in_s[t] : 0;
  s[t + 1024] = (t + 1024 < n) ? in_s[t + 1024] : 0;
  __syncthreads();
  for (int off = 1; off < 2048; off <<= 1) {
    int v0 = (t >= off) ? s[t - off] : 0;
    int v1 = ((t + 1024) >= off) ? s[t + 1024 - off] : 0;
    __syncthreads();
    s[t] += v0;
    s[t + 1024] += v1;
    __syncthreads();
  }
  if (t < n) out_s[t] = (t == 0) ? 0 : s[t - 1];
  const int u = t + 1024;
  if (u < n) out_s[u] = s[u - 1];
  if (t == 0) out_s[n] = s[n - 1];
}

__global__ __launch_bounds__(1024) void partition2(const int* __restrict__ src0,
                                                   const int* __restrict__ src1,
                                                   const int* __restrict__ dst0,
                                                   const int* __restrict__ dst1, int E, int chunk,
                                                   const int* __restrict__ hist,
                                                   const int* __restrict__ boff,
                                                   unsigned* __restrict__ ebufA,
                                                   unsigned* __restrict__ ebufB, int nbk) {
  const int side = blockIdx.y;
  const int* __restrict__ src = side ? src1 : src0;
  const int* __restrict__ dst = side ? dst1 : dst0;
  const int* __restrict__ boff_s = boff + side * (nbk + 1);
  unsigned* __restrict__ ebuf = side ? ebufB : ebufA;
  __shared__ int lbase[NBK_MAX];
  __shared__ int lcur[NBK_MAX];
  const int* row = hist + ((size_t)side * PART_BLOCKS + blockIdx.x) * nbk;
  for (int i = threadIdx.x; i < nbk; i += 1024) {
    lbase[i] = boff_s[i] + row[i];
    lcur[i] = 0;
  }
  __syncthreads();
  const int e0 = blockIdx.x * chunk;
  const int e1 = min(E, e0 + chunk);
  for (int e = e0 + threadIdx.x; e < e1; e += 1024) {
    int d = dst[e];
    int b = d >> 9;
    int pos = lbase[b] + atomicAdd(&lcur[b], 1);
    ebuf[pos] = ((unsigned)src[e] << 9) | (unsigned)(d & 511);
  }
}

__global__ __launch_bounds__(512) void bucket_csr2(const unsigned* __restrict__ ebufA,
                                                   const unsigned* __restrict__ ebufB,
                                                   const int* __restrict__ boff,
                                                   int* __restrict__ row_ptrA,
                                                   int* __restrict__ colA,
                                                   int* __restrict__ row_ptrB,
                                                   int* __restrict__ colB, int N, int E,
                                                   int nbk) {
  __shared__ int cnt[512], cur[512];
  const int side = blockIdx.y;
  const unsigned* __restrict__ ebuf = side ? ebufB : ebufA;
  const int* __restrict__ boff_s = boff + side * (nbk + 1);
  int* __restrict__ row_ptr = side ? row_ptrB : row_ptrA;
  int* __restrict__ col = side ? colB : colA;
  const int b = blockIdx.x;
  const int node0 = b << 9;
  const int nn = min(512, N - node0);
  const int es = boff_s[b], ee = boff_s[b + 1];
  const int t = threadIdx.x;
  cnt[t] = 0;
  __syncthreads();
  for (int e = es + t; e < ee; e += 512) atomicAdd(&cnt[ebuf[e] & 511u], 1);
  __syncthreads();
  for (int off = 1; off < 512; off <<= 1) {
    int v = (t >= off) ? cnt[t - off] : 0;
    __syncthreads();
    cnt[t] += v;
    __syncthreads();
  }
  int ex = (t == 0) ? 0 : cnt[t - 1];
  cur[t] = ex;
  if (t < nn) row_ptr[node0 + t] = es + ex;
  __syncthreads();
  for (int e = es + t; e < ee; e += 512) {
    unsigned u = ebuf[e];
    int li = (int)(u & 511u);
    int pos = es + atomicAdd(&cur[li], 1);
    col[pos] = (int)(u >> 9);
  }
  if (b == 0 && t == 0) row_ptr[N] = E;
}

// ---------------- MFMA linear (f16): y_bf16 = f16(BN-affine(h)) . W_f16 ----------------
// Input either fp32 (layer 1) or fp16 (h from previous layer). BN affine in fp32.
// A layout: A[m=lane&15][k=quad*8+j]; D layout: D[row=quad*4+r][col=lane&15].

template <int FIN, int FOUT, bool HAS_BN, bool IN_HALF>
__global__ __launch_bounds__(256) void lin_mfma(const void* __restrict__ xin,
                                                const float* __restrict__ W,
                                                const float* __restrict__ stats,
                                                const float* __restrict__ gamma,
                                                const float* __restrict__ beta, float invN,
                                                ushort_t* __restrict__ y, int n) {
  constexpr int KC = FIN / 32;   // k-chunks (FIN in {64,32})
  constexpr int FT = FOUT / 16;  // feature tiles
  __shared__ _Float16 Whf[FIN * FOUT];
  __shared__ float scv[FIN], ofv[FIN];
  const int tid = threadIdx.x;
  for (int i = tid; i < FIN * FOUT; i += 256) Whf[i] = (_Float16)W[i];
  for (int i = tid; i < FIN; i += 256) {
    if constexpr (HAS_BN) {
      float mu = stats[i] * invN;
      float var = stats[128 + i] * invN - mu * mu;
      float s = gamma[i] * rsqrtf(var + 1e-5f);
      scv[i] = s;
      ofv[i] = beta[i] - s * mu;
    } else {
      scv[i] = 1.f;
      ofv[i] = 0.f;
    }
  }
  __syncthreads();
  const int lane = tid & 63, wv = tid >> 6;
  const int colf = lane & 15, quad = lane >> 4, kbase = quad * 8;

  half8 Bf[FT][KC];
#pragma unroll
  for (int t = 0; t < FT; t++)
#pragma unroll
    for (int c = 0; c < KC; c++)
#pragma unroll
      for (int j = 0; j < 8; j++)
        Bf[t][c][j] = Whf[(c * 32 + kbase + j) * FOUT + t * 16 + colf];

  const floatx4 zero4 = {0.f, 0.f, 0.f, 0.f};
  const int ntiles = (n + 15) >> 4;
  for (int nt = blockIdx.x * 4 + wv; nt < ntiles; nt += gridDim.x * 4) {
    const int node0 = nt << 4;
    const int anode = node0 + colf;
    half8 Af[KC];
#pragma unroll
    for (int c = 0; c < KC; c++) {
      if (anode < n) {
        const int kk = c * 32 + kbase;
        if constexpr (IN_HALF) {
          const ushort_t* hp = (const ushort_t*)xin + (size_t)anode * FIN + kk;
          half8 hv = *(const half8*)hp;
#pragma unroll
          for (int j = 0; j < 8; j++)
            Af[c][j] = (_Float16)fmaf((float)hv[j], scv[kk + j], ofv[kk + j]);
        } else {
          const float* xp = (const float*)xin + (size_t)anode * FIN + kk;
          float4 xa = *(const float4*)xp;
          float4 xb = *(const float4*)(xp + 4);
          Af[c][0] = (_Float16)fmaf(xa.x, scv[kk + 0], ofv[kk + 0]);
          Af[c][1] = (_Float16)fmaf(xa.y, scv[kk + 1], ofv[kk + 1]);
          Af[c][2] = (_Float16)fmaf(xa.z, scv[kk + 2], ofv[kk + 2]);
          Af[c][3] = (_Float16)fmaf(xa.w, scv[kk + 3], ofv[kk + 3]);
          Af[c][4] = (_Float16)fmaf(xb.x, scv[kk + 4], ofv[kk + 4]);
          Af[c][5] = (_Float16)fmaf(xb.y, scv[kk + 5], ofv[kk + 5]);
          Af[c][6] = (_Float16)fmaf(xb.z, scv[kk + 6], ofv[kk + 6]);
          Af[c][7] = (_Float16)fmaf(xb.w, scv[kk + 7], ofv[kk + 7]);
        }
      } else {
        Af[c] = half8{0, 0, 0, 0, 0, 0, 0, 0};
      }
    }
#pragma unroll
    for (int t = 0; t < FT; t++) {
      floatx4 acc = zero4;
#pragma unroll
      for (int c = 0; c < KC; c++)
        acc = __builtin_amdgcn_mfma_f32_16x16x32_f16(Af[c], Bf[t][c], acc, 0, 0, 0);
#pragma unroll
      for (int r = 0; r < 4; r++) {
        const int row = node0 + quad * 4 + r;
        if (row < n) y[(size_t)row * FOUT + t * 16 + colf] = f2bf(acc[r]);
      }
    }
  }
}

// ---------------- MFMA second linear: h_fp16 = m_bf16 . W2_bf16 + b2 (+ BN stats fp32) -----

template <int F>
__global__ __launch_bounds__(256) void lin2s_mfma(const ushort_t* __restrict__ m,
                                                  const float* __restrict__ W,
                                                  const float* __restrict__ b,
                                                  ushort_t* __restrict__ h,
                                                  float* __restrict__ stats, int n) {
  constexpr int KC = (F + 31) / 32;  // 2,1,1
  constexpr int FT = F / 16;         // 4,2,1
  __shared__ ushort_t Wbf[F * F];
  __shared__ float bs[F], ls[F], lsq[F];
  const int tid = threadIdx.x;
  for (int i = tid; i < F * F; i += 256) Wbf[i] = f2bf(W[i]);
  if (tid < F) {
    bs[tid] = b[tid];
    ls[tid] = 0.f;
    lsq[tid] = 0.f;
  }
  __syncthreads();
  const int lane = tid & 63, wv = tid >> 6;
  const int colf = lane & 15, quad = lane >> 4, kbase = quad * 8;

  short8 Bf[FT][KC];
#pragma unroll
  for (int t = 0; t < FT; t++)
#pragma unroll
    for (int c = 0; c < KC; c++)
#pragma unroll
      for (int j = 0; j < 8; j++) {
        const int k = c * 32 + kbase + j;
        Bf[t][c][j] = (k < F) ? (short)Wbf[k * F + t * 16 + colf] : (short)0;
      }

  const floatx4 zero4 = {0.f, 0.f, 0.f, 0.f};
  float ssum[FT], ssq[FT];
#pragma unroll
  for (int t = 0; t < FT; t++) {
    ssum[t] = 0.f;
    ssq[t] = 0.f;
  }

  const int ntiles = (n + 15) >> 4;
  for (int nt = blockIdx.x * 4 + wv; nt < ntiles; nt += gridDim.x * 4) {
    const int node0 = nt << 4;
    const int anode = node0 + colf;
    short8 Af[KC];
#pragma unroll
    for (int c = 0; c < KC; c++) {
      const int kk = c * 32 + kbase;
      if (anode < n && kk < F)
        Af[c] = *(const short8*)(m + (size_t)anode * F + kk);
      else
        Af[c] = short8{0, 0, 0, 0, 0, 0, 0, 0};
    }
#pragma unroll
    for (int t = 0; t < FT; t++) {
      floatx4 acc = zero4;
#pragma unroll
      for (int c = 0; c < KC; c++)
        acc = __builtin_amdgcn_mfma_f32_16x16x32_bf16(Af[c], Bf[t][c], acc, 0, 0, 0);
      const float bv = bs[t * 16 + colf];
#pragma unroll
      for (int r = 0; r < 4; r++) {
        const int row = node0 + quad * 4 + r;
        if (row < n) {
          float o = acc[r] + bv;
          h[(size_t)row * F + t * 16 + colf] = f2h_bits(o);
          ssum[t] += o;
          ssq[t] += o * o;
        }
      }
    }
  }
#pragma unroll
  for (int t = 0; t < FT; t++) {
    atomicAdd(&ls[t * 16 + colf], ssum[t]);
    atomicAdd(&lsq[t * 16 + colf], ssq[t]);
  }
  __syncthreads();
  if (tid < F) {
    atomicAdd(&stats[tid], ls[tid]);
    atomicAdd(&stats[128 + tid], lsq[tid]);
  }
}

// ---------------- Gather (bf16 rows, fp32 accum): m_bf16 = ReLU((1+eps)*y_i + sum y_j + b1) ----

template <int F>
__global__ __launch_bounds__(256) void aggrelu_b(const ushort_t* __restrict__ y,
                                                 const int* __restrict__ row_ptr,
                                                 const int* __restrict__ col,
                                                 const float* __restrict__ epsp,
                                                 const float* __restrict__ b1,
                                                 ushort_t* __restrict__ m, int n) {
  constexpr int LPN = F / 8;      // 16B bf16x8 per lane
  constexpr int NPB = 256 / LPN;  // 32 / 64 / 128 nodes per block
  const int tid = threadIdx.x;
  const int ln = tid / LPN;
  const int fl = tid % LPN;
  const float e1 = 1.0f + epsp[0];
  const float4 b1a = ((const float4*)b1)[fl * 2];
  const float4 b1b = ((const float4*)b1)[fl * 2 + 1];

  const int node = blockIdx.x * NPB + ln;
  if (node >= n) return;
  const uint4* yr = (const uint4*)y;
  const size_t rowi = (size_t)node * LPN + fl;
  const int rs = row_ptr[node], re = row_ptr[node + 1];

  float acc[8];
#pragma unroll
  for (int j = 0; j < 8; j++) acc[j] = 0.f;

  auto addv = [&](uint4 v) {
    acc[0] += __uint_as_float(v.x << 16);
    acc[1] += __uint_as_float(v.x & 0xffff0000u);
    acc[2] += __uint_as_float(v.y << 16);
    acc[3] += __uint_as_float(v.y & 0xffff0000u);
    acc[4] += __uint_as_float(v.z << 16);
    acc[5] += __uint_as_float(v.z & 0xffff0000u);
    acc[6] += __uint_as_float(v.w << 16);
    acc[7] += __uint_as_float(v.w & 0xffff0000u);
  };

  int e = rs;
  for (; e + 8 <= re; e += 8) {
    int c0 = col[e], c1 = col[e + 1], c2 = col[e + 2], c3 = col[e + 3];
    int c4 = col[e + 4], c5 = col[e + 5], c6 = col[e + 6], c7 = col[e + 7];
    uint4 v0 = yr[(size_t)c0 * LPN + fl];
    uint4 v1 = yr[(size_t)c1 * LPN + fl];
    uint4 v2 = yr[(size_t)c2 * LPN + fl];
    uint4 v3 = yr[(size_t)c3 * LPN + fl];
    uint4 v4 = yr[(size_t)c4 * LPN + fl];
    uint4 v5 = yr[(size_t)c5 * LPN + fl];
    uint4 v6 = yr[(size_t)c6 * LPN + fl];
    uint4 v7 = yr[(size_t)c7 * LPN + fl];
    addv(v0);
    addv(v1);
    addv(v2);
    addv(v3);
    addv(v4);
    addv(v5);
    addv(v6);
    addv(v7);
  }
  for (; e + 4 <= re; e += 4) {
    int c0 = col[e], c1 = col[e + 1], c2 = col[e + 2], c3 = col[e + 3];
    uint4 v0 = yr[(size_t)c0 * LPN + fl];
    uint4 v1 = yr[(size_t)c1 * LPN + fl];
    uint4 v2 = yr[(size_t)c2 * LPN + fl];
    uint4 v3 = yr[(size_t)c3 * LPN + fl];
    addv(v0);
    addv(v1);
    addv(v2);
    addv(v3);
  }
  for (; e < re; e++) addv(yr[(size_t)col[e] * LPN + fl]);

  uint4 sv = yr[rowi];
  float r0, r1, r2, r3, r4, r5, r6, r7;
  r0 = fmaxf(fmaf(e1, __uint_as_float(sv.x << 16), acc[0]) + b1a.x, 0.f);
  r1 = fmaxf(fmaf(e1, __uint_as_float(sv.x & 0xffff0000u), acc[1]) + b1a.y, 0.f);
  r2 = fmaxf(fmaf(e1, __uint_as_float(sv.y << 16), acc[2]) + b1a.z, 0.f);
  r3 = fmaxf(fmaf(e1, __uint_as_float(sv.y & 0xffff0000u), acc[3]) + b1a.w, 0.f);
  r4 = fmaxf(fmaf(e1, __uint_as_float(sv.z << 16), acc[4]) + b1b.x, 0.f);
  r5 = fmaxf(fmaf(e1, __uint_as_float(sv.z & 0xffff0000u), acc[5]) + b1b.y, 0.f);
  r6 = fmaxf(fmaf(e1, __uint_as_float(sv.w << 16), acc[6]) + b1b.z, 0.f);
  r7 = fmaxf(fmaf(e1, __uint_as_float(sv.w & 0xffff0000u), acc[7]) + b1b.w, 0.f);
  uint4 o;
  o.x = (unsigned)f2bf(r0) | ((unsigned)f2bf(r1) << 16);
  o.y = (unsigned)f2bf(r2) | ((unsigned)f2bf(r3) << 16);
  o.z = (unsigned)f2bf(r4) | ((unsigned)f2bf(r5) << 16);
  o.w = (unsigned)f2bf(r6) | ((unsigned)f2bf(r7) << 16);
  ((uint4*)m)[rowi] = o;
}

// ---------------- Fused readout: gstart search + BN3-affine + mean + att-c + gated pool ----
// h3 is fp16.

__global__ __launch_bounds__(256) void readout_fused(
    const ushort_t* __restrict__ h3, const int* __restrict__ batch, int n,
    const float* __restrict__ stats, const float* __restrict__ gamma,
    const float* __restrict__ beta, float invN, const float* __restrict__ attW,
    const float* __restrict__ attb, float* __restrict__ hg, int ng) {
  __shared__ float sM[16], oM[16], red[16][17], meanM[16], cM[16];
  __shared__ int seg[2];
  const int tid = threadIdx.x;
  const int g = blockIdx.x;
  const int f = tid & 15, slot = tid >> 4;
  if (tid < 16) {
    float mu = stats[tid] * invN;
    float var = stats[128 + tid] * invN - mu * mu;
    float s = gamma[tid] * rsqrtf(var + 1e-5f);
    sM[tid] = s;
    oM[tid] = beta[tid] - s * mu;
  }
  if (tid >= 32 && tid < 34) {
    const int key = g + (tid - 32);
    int lo = 0, hi = n;
    while (lo < hi) {
      int mid = (lo + hi) >> 1;
      if (batch[mid] < key) lo = mid + 1; else hi = mid;
    }
    seg[tid - 32] = lo;
  }
  __syncthreads();
  const int s0 = seg[0], e0 = seg[1];
  const float sf = sM[f], of = oM[f];

  float acc = 0.f;
  for (int node = s0 + slot; node < e0; node += 16)
    acc += fmaf(h2f_bits(h3[(size_t)node * 16 + f]), sf, of);
  red[slot][f] = acc;
  __syncthreads();
  if (tid < 16) {
    float t = 0.f;
    for (int s = 0; s < 16; s++) t += red[s][tid];
    meanM[tid] = t / fmaxf((float)(e0 - s0), 1.f);
  }
  __syncthreads();
  if (tid < 16) {
    float a = attb[tid];
    for (int k = 0; k < 16; k++) a += meanM[k] * attW[k * 16 + tid];
    cM[tid] = 1.f / (1.f + expf(-a));
  }
  __syncthreads();
  const float cf = cM[f];
  float acc2 = 0.f;
  for (int node = s0 + slot; node < e0; node += 16) {
    float xv = fmaf(h2f_bits(h3[(size_t)node * 16 + f]), sf, of);
    float p = xv * cf;
    for (int m = 8; m >= 1; m >>= 1) p += __shfl_xor(p, m, 16);
    acc2 += xv / (1.f + expf(-p));
  }
  red[slot][f] = acc2;
  __syncthreads();
  if (tid < 16) {
    float t = 0.f;
    for (int s = 0; s < 16; s++) t += red[s][tid];
    hg[g * 16 + tid] = t;
  }
}

// ---------------- EFN + final: 16 lanes per graph, weights + vectors in LDS ----------------

__global__ __launch_bounds__(256) void final3_kernel(
    const float* __restrict__ hgA, const float* __restrict__ hgB, const float* __restrict__ aW1,
    const float* __restrict__ ab1, const float* __restrict__ aW2, const float* __restrict__ ab2,
    const float* __restrict__ mW, const float* __restrict__ mb, const float* __restrict__ fcW1,
    const float* __restrict__ fcb1, const float* __restrict__ fcW2,
    const float* __restrict__ fcb2, float* __restrict__ out, int ng) {
  __shared__ float aW1s[256], aW2s[256], mWs[512], fcW1s[128];
  __shared__ float ab1s[8], ab2s[32], mbs[16], fcb1s[8], fcW2s[8];
  __shared__ float fcb2s;
  __shared__ float hb[16][33], m8b[16][9], encb[16][33], abb[16][17], tb[16][9];
  const int tid = threadIdx.x;
  aW1s[tid] = aW1[tid];
  aW2s[tid] = aW2[tid];
  mWs[tid] = mW[tid];
  mWs[256 + tid] = mW[256 + tid];
  if (tid < 128) fcW1s[tid] = fcW1[tid];
  if (tid < 8) {
    ab1s[tid] = ab1[tid];
    fcb1s[tid] = fcb1[tid];
    fcW2s[tid] = fcW2[tid];
  }
  if (tid < 32) ab2s[tid] = ab2[tid];
  if (tid < 16) mbs[tid] = mb[tid];
  if (tid == 0) fcb2s = fcb2[0];
  __syncthreads();

  const int g = tid >> 4;
  const int l = tid & 15;
  const int gg = blockIdx.x * 16 + g;
  const bool valid = gg < ng;
  const float hiv = valid ? hgA[gg * 16 + l] : 0.f;
  const float hjv = valid ? hgB[gg * 16 + l] : 0.f;
  float res[3];

#pragma unroll
  for (int p = 0; p < 3; p++) {
    float ha = (p == 2) ? hjv : hiv;
    float h2 = (p == 1) ? hiv : hjv;
    hb[g][l] = ha;
    hb[g][16 + l] = h2;
    __syncthreads();
    if (l < 8) {
      float t = ab1s[l];
#pragma unroll
      for (int k = 0; k < 32; k++) t += hb[g][k] * aW1s[k * 8 + l];
      m8b[g][l] = fmaxf(t, 0.f);
    }
    __syncthreads();
    float e0 = ab2s[l], e1 = ab2s[16 + l];
#pragma unroll
    for (int k = 0; k < 8; k++) {
      float mv = m8b[g][k];
      e0 += mv * aW2s[k * 32 + l];
      e1 += mv * aW2s[k * 32 + 16 + l];
    }
    float a0 = tanhf(e0), a1 = tanhf(e1);
    encb[g][l] = fmaf(a0, ha, ha);
    encb[g][16 + l] = fmaf(a1, h2, h2);
    __syncthreads();
    float o = mbs[l];
#pragma unroll
    for (int k = 0; k < 32; k++) o += encb[g][k] * mWs[k * 16 + l];
    res[p] = fmaxf(o, 0.f);
    __syncthreads();
  }

  if (valid) {
    out[ng + gg * 16 + l] = res[0] - res[2];            // h_Ab = AB - BB
    out[ng + ng * 16 + gg * 16 + l] = res[0] - res[1];  // h_aB = AB - AA
  }
  abb[g][l] = res[0];
  __syncthreads();
  if (l < 8) {
    float t = fcb1s[l];
#pragma unroll
    for (int k = 0; k < 16; k++) t += abb[g][k] * fcW1s[k * 8 + l];
    tb[g][l] = fmaxf(t, 0.f);
  }
  __syncthreads();
  if (l == 0 && valid) {
    float sc = fcb2s;
#pragma unroll
    for (int o = 0; o < 8; o++) sc += tb[g][o] * fcW2s[o];
    out[gg] = sc;
  }
}

// ---------------- Launch ----------------

extern "C" void kernel_launch(void* const* d_in, const int* in_sizes, int n_in, void* d_out,
                              int out_size, void* d_ws, size_t ws_size, hipStream_t stream) {
  (void)n_in;
  (void)out_size;
  (void)ws_size;
  const int N = in_sizes[0] / 64;
  const int E = in_sizes[2] / 2;
  const int NG = NGRAPH;
  const int NBK = (N + 511) >> 9;
  const int CHUNK = (E + PART_BLOCKS - 1) / PART_BLOCKS;

  char* w = (char*)d_ws;
  auto alloc = [&](size_t bytes) -> void* {
    void* p = (void*)w;
    w += (bytes + 255) & ~(size_t)255;
    return p;
  };
  int* row_ptrA = (int*)alloc((size_t)(N + 1) * 4);
  int* colA = (int*)alloc((size_t)E * 4);
  int* row_ptrB = (int*)alloc((size_t)(N + 1) * 4);
  int* colB = (int*)alloc((size_t)E * 4);
  int* hist = (int*)alloc((size_t)2 * PART_BLOCKS * NBK * 4);
  int* totals = (int*)alloc((size_t)2 * NBK * 4);
  int* boff = (int*)alloc((size_t)2 * (NBK + 1) * 4);
  ushort_t* bufA = (ushort_t*)alloc((size_t)N * 64 * 2);  // 25.6 MB
  ushort_t* bufB = (ushort_t*)alloc((size_t)N * 64 * 2);  // 25.6 MB
  float* stats = (float*)alloc((size_t)2 * 768 * 4);
  float* hgA = (float*)alloc((size_t)NG * 16 * 4);
  float* hgB = (float*)alloc((size_t)NG * 16 * 4);

  // Aliases (disjoint live ranges). y/m bf16, h fp16:
  unsigned* ebufA = (unsigned*)bufA;        // E*4 = 12.8 MB; dead before layer 1
  unsigned* ebufB = ebufA + E;              // E*4 = 12.8 MB
  ushort_t* y1 = bufB;                      // bf16 N*64
  ushort_t* m1 = bufA;                      // bf16 N*64 (over dead ebufs)
  ushort_t* h1 = bufB;                      // fp16 N*64 (y1 dead)
  ushort_t* y2 = bufA;                      // bf16 N*32 (m1 dead)
  ushort_t* m2 = bufA + (size_t)N * 32;     // bf16 N*32
  ushort_t* h2 = bufB;                      // fp16 N*32 (h1 dead)
  ushort_t* y3 = bufA;                      // bf16 N*16 (y2/m2 dead)
  ushort_t* m3 = bufA + (size_t)N * 16;     // bf16 N*16
  ushort_t* h3 = bufB;                      // fp16 N*16 (h2 dead)

  const int* esrc0 = (const int*)d_in[2];
  const int* edst0 = esrc0 + E;
  const int* esrc1 = (const int*)d_in[3];
  const int* edst1 = esrc1 + E;
  const float* attW = (const float*)d_in[27];
  const float* attb = (const float*)d_in[28];
  const float invN = 1.0f / (float)N;

  // ---- bucketed CSR build, BOTH sides batched (blockIdx.y = side) ----
  bucket_hist2<<<dim3(PART_BLOCKS, 2), 1024, 0, stream>>>(edst0, edst1, E, CHUNK, hist, NBK);
  colscan_par2<<<dim3(NBK, 2), PART_BLOCKS, 0, stream>>>(hist, NBK, totals);
  scan_small2<<<2, 1024, 0, stream>>>(totals, NBK, boff);
  partition2<<<dim3(PART_BLOCKS, 2), 1024, 0, stream>>>(esrc0, esrc1, edst0, edst1, E, CHUNK,
                                                        hist, boff, ebufA, ebufB, NBK);
  bucket_csr2<<<dim3(NBK, 2), 512, 0, stream>>>(ebufA, ebufB, boff, row_ptrA, colA, row_ptrB,
                                                colB, N, E, NBK);
  hipMemsetAsync(stats, 0, 2 * 768 * 4, stream);

  for (int s = 0; s < 2; s++) {
    const float* x0 = (const float*)d_in[s];
    const int* batch = (const int*)d_in[4 + s];
    const int* row_ptr = s ? row_ptrB : row_ptrA;
    const int* col = s ? colB : colA;
    float* st = stats + s * 768;
    float* hg = s ? hgB : hgA;

    // ---- layer 1 ----
    lin_mfma<64, 64, false, false><<<512, 256, 0, stream>>>(
        x0, (const float*)d_in[7], nullptr, nullptr, nullptr, invN, y1, N);
    aggrelu_b<64><<<(N + 31) / 32, 256, 0, stream>>>(
        y1, row_ptr, col, (const float*)d_in[6], (const float*)d_in[8], m1, N);
    lin2s_mfma<64><<<512, 256, 0, stream>>>(m1, (const float*)d_in[9], (const float*)d_in[10],
                                            h1, st, N);

    // ---- layer 2 ----
    lin_mfma<64, 32, true, true><<<512, 256, 0, stream>>>(
        h1, (const float*)d_in[14], st, (const float*)d_in[11], (const float*)d_in[12], invN,
        y2, N);
    aggrelu_b<32><<<(N + 63) / 64, 256, 0, stream>>>(
        y2, row_ptr, col, (const float*)d_in[13], (const float*)d_in[15], m2, N);
    lin2s_mfma<32><<<512, 256, 0, stream>>>(m2, (const float*)d_in[16], (const float*)d_in[17],
                                            h2, st + 256, N);

    // ---- layer 3 ----
    lin_mfma<32, 16, true, true><<<512, 256, 0, stream>>>(
        h2, (const float*)d_in[21], st + 256, (const float*)d_in[18], (const float*)d_in[19],
        invN, y3, N);
    aggrelu_b<16><<<(N + 127) / 128, 256, 0, stream>>>(
        y3, row_ptr, col, (const float*)d_in[20], (const float*)d_in[22], m3, N);
    lin2s_mfma<16><<<512, 256, 0, stream>>>(m3, (const float*)d_in[23], (const float*)d_in[24],
                                            h3, st + 512, N);

    // ---- fused readout (gstart search inlined; BN3 folded; h3 fp16) ----
    readout_fused<<<NG, 256, 0, stream>>>(h3, batch, N, st + 512, (const float*)d_in[25],
                                          (const float*)d_in[26], invN, attW, attb, hg, NG);
  }

  final3_kernel<<<(NG + 15) / 16, 256, 0, stream>>>(
      hgA, hgB, (const float*)d_in[29], (const float*)d_in[30], (const float*)d_in[31],
      (const float*)d_in[32], (const float*)d_in[33], (const float*)d_in[34],
      (const float*)d_in[35], (const float*)d_in[36], (const float*)d_in[37],
      (const float*)d_in[38], (float*)d_out, NG);
}

// Round 7
// 882.592 us; speedup vs baseline: 1.0146x; 1.0146x over previous
//
#include <hip/hip_runtime.h>
#include <math.h>

#define NGRAPH 1000
#define BKSHIFT 11        // 2048-node buckets
#define BKMASK 2047
#define NBK_MAX 128       // ceil(200000/2048)=98
#define PART_BLOCKS 256

typedef unsigned short ushort_t;
typedef __attribute__((ext_vector_type(8))) short short8;     // 8 bf16 (4 VGPRs)
typedef __attribute__((ext_vector_type(8))) _Float16 half8;   // 8 fp16 (4 VGPRs)
typedef __attribute__((ext_vector_type(4))) float floatx4;    // MFMA accumulator

static __device__ inline ushort_t f2bf(float f) {
  unsigned u = __float_as_uint(f);
  u = (u + 0x7fffu + ((u >> 16) & 1u)) >> 16;  // RNE
  return (ushort_t)u;
}
static __device__ inline ushort_t f2h_bits(float f) {
  return __builtin_bit_cast(ushort_t, (_Float16)f);  // RNE
}
static __device__ inline float h2f_bits(ushort_t u) {
  return (float)__builtin_bit_cast(_Float16, u);
}

// ---------------- Bucketed, atomic-free CSR build (BOTH sides batched) ----------------
// Buckets are 2048 nodes (shift 11). ebuf entries packed to 4B:
// (src << 11) | (dst & 2047)  -- src < 2^18, fits 29 bits.  blockIdx.y = side.
// Bucket size chosen so per-(block,bucket) write runs are ~512B and the live
// partial-line footprint (blocks x buckets x 64B) stays L2-resident.

__global__ __launch_bounds__(1024) void bucket_hist2(const int* __restrict__ dst0,
                                                     const int* __restrict__ dst1, int E,
                                                     int chunk, int* __restrict__ hist, int nbk) {
  const int side = blockIdx.y;
  const int* __restrict__ dst = side ? dst1 : dst0;
  __shared__ int lh[NBK_MAX];
  for (int i = threadIdx.x; i < nbk; i += 1024) lh[i] = 0;
  __syncthreads();
  const int e0 = blockIdx.x * chunk;
  const int e1 = min(E, e0 + chunk);
  for (int e = e0 + threadIdx.x; e < e1; e += 1024) atomicAdd(&lh[dst[e] >> BKSHIFT], 1);
  __syncthreads();
  int* row = hist + ((size_t)side * PART_BLOCKS + blockIdx.x) * nbk;
  for (int i = threadIdx.x; i < nbk; i += 1024) row[i] = lh[i];
}

// Parallel column scan: one block per (bucket, side), 256 threads = PART_BLOCKS.
__global__ __launch_bounds__(PART_BLOCKS) void colscan_par2(int* __restrict__ hist, int nbk,
                                                            int* __restrict__ totals) {
  __shared__ int s[PART_BLOCKS];
  const int side = blockIdx.y;
  int* __restrict__ hist_s = hist + (size_t)side * PART_BLOCKS * nbk;
  int* __restrict__ totals_s = totals + side * nbk;
  const int b = blockIdx.x;   // bucket
  const int t = threadIdx.x;  // partition block
  s[t] = hist_s[(size_t)t * nbk + b];
  __syncthreads();
  for (int off = 1; off < PART_BLOCKS; off <<= 1) {
    int u = (t >= off) ? s[t - off] : 0;
    __syncthreads();
    s[t] += u;
    __syncthreads();
  }
  const int exc = (t == 0) ? 0 : s[t - 1];
  hist_s[(size_t)t * nbk + b] = exc;
  if (t == PART_BLOCKS - 1) totals_s[b] = s[PART_BLOCKS - 1];
}

__global__ __launch_bounds__(1024) void scan_small2(const int* __restrict__ in, int n,
                                                    int* __restrict__ out) {
  __shared__ int s[2048];
  const int side = blockIdx.x;
  const int* __restrict__ in_s = in + side * n;
  int* __restrict__ out_s = out + side * (n + 1);
  const int t = threadIdx.x;
  s[t] = (t < n) ? in_s[t] : 0;
  s[t + 1024] = (t + 1024 < n) ? in_s[t + 1024] : 0;
  __syncthreads();
  for (int off = 1; off < 2048; off <<= 1) {
    int v0 = (t >= off) ? s[t - off] : 0;
    int v1 = ((t + 1024) >= off) ? s[t + 1024 - off] : 0;
    __syncthreads();
    s[t] += v0;
    s[t + 1024] += v1;
    __syncthreads();
  }
  if (t < n) out_s[t] = (t == 0) ? 0 : s[t - 1];
  const int u = t + 1024;
  if (u < n) out_s[u] = s[u - 1];
  if (t == 0) out_s[n] = s[n - 1];
}

__global__ __launch_bounds__(1024) void partition2(const int* __restrict__ src0,
                                                   const int* __restrict__ src1,
                                                   const int* __restrict__ dst0,
                                                   const int* __restrict__ dst1, int E, int chunk,
                                                   const int* __restrict__ hist,
                                                   const int* __restrict__ boff,
                                                   unsigned* __restrict__ ebufA,
                                                   unsigned* __restrict__ ebufB, int nbk) {
  const int side = blockIdx.y;
  const int* __restrict__ src = side ? src1 : src0;
  const int* __restrict__ dst = side ? dst1 : dst0;
  const int* __restrict__ boff_s = boff + side * (nbk + 1);
  unsigned* __restrict__ ebuf = side ? ebufB : ebufA;
  __shared__ int lbase[NBK_MAX];
  __shared__ int lcur[NBK_MAX];
  const int* row = hist + ((size_t)side * PART_BLOCKS + blockIdx.x) * nbk;
  for (int i = threadIdx.x; i < nbk; i += 1024) {
    lbase[i] = boff_s[i] + row[i];
    lcur[i] = 0;
  }
  __syncthreads();
  const int e0 = blockIdx.x * chunk;
  const int e1 = min(E, e0 + chunk);
  for (int e = e0 + threadIdx.x; e < e1; e += 1024) {
    int d = dst[e];
    int b = d >> BKSHIFT;
    int pos = lbase[b] + atomicAdd(&lcur[b], 1);
    ebuf[pos] = ((unsigned)src[e] << BKSHIFT) | (unsigned)(d & BKMASK);
  }
}

__global__ __launch_bounds__(1024) void bucket_csr2(const unsigned* __restrict__ ebufA,
                                                    const unsigned* __restrict__ ebufB,
                                                    const int* __restrict__ boff,
                                                    int* __restrict__ row_ptrA,
                                                    int* __restrict__ colA,
                                                    int* __restrict__ row_ptrB,
                                                    int* __restrict__ colB, int N, int E,
                                                    int nbk) {
  __shared__ int cnt[2048], cur[2048];
  const int side = blockIdx.y;
  const unsigned* __restrict__ ebuf = side ? ebufB : ebufA;
  const int* __restrict__ boff_s = boff + side * (nbk + 1);
  int* __restrict__ row_ptr = side ? row_ptrB : row_ptrA;
  int* __restrict__ col = side ? colB : colA;
  const int b = blockIdx.x;
  const int node0 = b << BKSHIFT;
  const int nn = min(2048, N - node0);
  const int es = boff_s[b], ee = boff_s[b + 1];
  const int t = threadIdx.x;
  cnt[t] = 0;
  cnt[t + 1024] = 0;
  __syncthreads();
  for (int e = es + t; e < ee; e += 1024) atomicAdd(&cnt[ebuf[e] & (unsigned)BKMASK], 1);
  __syncthreads();
  // inclusive Hillis-Steele over 2048 counters (2 per thread, read-sync-write)
  for (int off = 1; off < 2048; off <<= 1) {
    int v0 = (t >= off) ? cnt[t - off] : 0;
    int v1 = ((t + 1024) >= off) ? cnt[t + 1024 - off] : 0;
    __syncthreads();
    cnt[t] += v0;
    cnt[t + 1024] += v1;
    __syncthreads();
  }
  const int ex0 = (t == 0) ? 0 : cnt[t - 1];
  const int ex1 = cnt[t + 1023];
  cur[t] = ex0;
  cur[t + 1024] = ex1;
  if (t < nn) row_ptr[node0 + t] = es + ex0;
  if (t + 1024 < nn) row_ptr[node0 + t + 1024] = es + ex1;
  __syncthreads();
  for (int e = es + t; e < ee; e += 1024) {
    unsigned u = ebuf[e];
    int li = (int)(u & (unsigned)BKMASK);
    int pos = es + atomicAdd(&cur[li], 1);
    col[pos] = (int)(u >> BKSHIFT);
  }
  if (b == 0 && t == 0) row_ptr[N] = E;
}

// ---------------- MFMA linear (f16): y_bf16 = f16(BN-affine(h)) . W_f16 ----------------
// Input either fp32 (layer 1) or fp16 (h from previous layer). BN affine in fp32.
// A layout: A[m=lane&15][k=quad*8+j]; D layout: D[row=quad*4+r][col=lane&15].

template <int FIN, int FOUT, bool HAS_BN, bool IN_HALF>
__global__ __launch_bounds__(256) void lin_mfma(const void* __restrict__ xin,
                                                const float* __restrict__ W,
                                                const float* __restrict__ stats,
                                                const float* __restrict__ gamma,
                                                const float* __restrict__ beta, float invN,
                                                ushort_t* __restrict__ y, int n) {
  constexpr int KC = FIN / 32;   // k-chunks (FIN in {64,32})
  constexpr int FT = FOUT / 16;  // feature tiles
  __shared__ _Float16 Whf[FIN * FOUT];
  __shared__ float scv[FIN], ofv[FIN];
  const int tid = threadIdx.x;
  for (int i = tid; i < FIN * FOUT; i += 256) Whf[i] = (_Float16)W[i];
  for (int i = tid; i < FIN; i += 256) {
    if constexpr (HAS_BN) {
      float mu = stats[i] * invN;
      float var = stats[128 + i] * invN - mu * mu;
      float s = gamma[i] * rsqrtf(var + 1e-5f);
      scv[i] = s;
      ofv[i] = beta[i] - s * mu;
    } else {
      scv[i] = 1.f;
      ofv[i] = 0.f;
    }
  }
  __syncthreads();
  const int lane = tid & 63, wv = tid >> 6;
  const int colf = lane & 15, quad = lane >> 4, kbase = quad * 8;

  half8 Bf[FT][KC];
#pragma unroll
  for (int t = 0; t < FT; t++)
#pragma unroll
    for (int c = 0; c < KC; c++)
#pragma unroll
      for (int j = 0; j < 8; j++)
        Bf[t][c][j] = Whf[(c * 32 + kbase + j) * FOUT + t * 16 + colf];

  const floatx4 zero4 = {0.f, 0.f, 0.f, 0.f};
  const int ntiles = (n + 15) >> 4;
  for (int nt = blockIdx.x * 4 + wv; nt < ntiles; nt += gridDim.x * 4) {
    const int node0 = nt << 4;
    const int anode = node0 + colf;
    half8 Af[KC];
#pragma unroll
    for (int c = 0; c < KC; c++) {
      if (anode < n) {
        const int kk = c * 32 + kbase;
        if constexpr (IN_HALF) {
          const ushort_t* hp = (const ushort_t*)xin + (size_t)anode * FIN + kk;
          half8 hv = *(const half8*)hp;
#pragma unroll
          for (int j = 0; j < 8; j++)
            Af[c][j] = (_Float16)fmaf((float)hv[j], scv[kk + j], ofv[kk + j]);
        } else {
          const float* xp = (const float*)xin + (size_t)anode * FIN + kk;
          float4 xa = *(const float4*)xp;
          float4 xb = *(const float4*)(xp + 4);
          Af[c][0] = (_Float16)fmaf(xa.x, scv[kk + 0], ofv[kk + 0]);
          Af[c][1] = (_Float16)fmaf(xa.y, scv[kk + 1], ofv[kk + 1]);
          Af[c][2] = (_Float16)fmaf(xa.z, scv[kk + 2], ofv[kk + 2]);
          Af[c][3] = (_Float16)fmaf(xa.w, scv[kk + 3], ofv[kk + 3]);
          Af[c][4] = (_Float16)fmaf(xb.x, scv[kk + 4], ofv[kk + 4]);
          Af[c][5] = (_Float16)fmaf(xb.y, scv[kk + 5], ofv[kk + 5]);
          Af[c][6] = (_Float16)fmaf(xb.z, scv[kk + 6], ofv[kk + 6]);
          Af[c][7] = (_Float16)fmaf(xb.w, scv[kk + 7], ofv[kk + 7]);
        }
      } else {
        Af[c] = half8{0, 0, 0, 0, 0, 0, 0, 0};
      }
    }
#pragma unroll
    for (int t = 0; t < FT; t++) {
      floatx4 acc = zero4;
#pragma unroll
      for (int c = 0; c < KC; c++)
        acc = __builtin_amdgcn_mfma_f32_16x16x32_f16(Af[c], Bf[t][c], acc, 0, 0, 0);
#pragma unroll
      for (int r = 0; r < 4; r++) {
        const int row = node0 + quad * 4 + r;
        if (row < n) y[(size_t)row * FOUT + t * 16 + colf] = f2bf(acc[r]);
      }
    }
  }
}

// ---------------- MFMA second linear: h_fp16 = m_bf16 . W2_bf16 + b2 (+ BN stats fp32) -----

template <int F>
__global__ __launch_bounds__(256) void lin2s_mfma(const ushort_t* __restrict__ m,
                                                  const float* __restrict__ W,
                                                  const float* __restrict__ b,
                                                  ushort_t* __restrict__ h,
                                                  float* __restrict__ stats, int n) {
  constexpr int KC = (F + 31) / 32;  // 2,1,1
  constexpr int FT = F / 16;         // 4,2,1
  __shared__ ushort_t Wbf[F * F];
  __shared__ float bs[F], ls[F], lsq[F];
  const int tid = threadIdx.x;
  for (int i = tid; i < F * F; i += 256) Wbf[i] = f2bf(W[i]);
  if (tid < F) {
    bs[tid] = b[tid];
    ls[tid] = 0.f;
    lsq[tid] = 0.f;
  }
  __syncthreads();
  const int lane = tid & 63, wv = tid >> 6;
  const int colf = lane & 15, quad = lane >> 4, kbase = quad * 8;

  short8 Bf[FT][KC];
#pragma unroll
  for (int t = 0; t < FT; t++)
#pragma unroll
    for (int c = 0; c < KC; c++)
#pragma unroll
      for (int j = 0; j < 8; j++) {
        const int k = c * 32 + kbase + j;
        Bf[t][c][j] = (k < F) ? (short)Wbf[k * F + t * 16 + colf] : (short)0;
      }

  const floatx4 zero4 = {0.f, 0.f, 0.f, 0.f};
  float ssum[FT], ssq[FT];
#pragma unroll
  for (int t = 0; t < FT; t++) {
    ssum[t] = 0.f;
    ssq[t] = 0.f;
  }

  const int ntiles = (n + 15) >> 4;
  for (int nt = blockIdx.x * 4 + wv; nt < ntiles; nt += gridDim.x * 4) {
    const int node0 = nt << 4;
    const int anode = node0 + colf;
    short8 Af[KC];
#pragma unroll
    for (int c = 0; c < KC; c++) {
      const int kk = c * 32 + kbase;
      if (anode < n && kk < F)
        Af[c] = *(const short8*)(m + (size_t)anode * F + kk);
      else
        Af[c] = short8{0, 0, 0, 0, 0, 0, 0, 0};
    }
#pragma unroll
    for (int t = 0; t < FT; t++) {
      floatx4 acc = zero4;
#pragma unroll
      for (int c = 0; c < KC; c++)
        acc = __builtin_amdgcn_mfma_f32_16x16x32_bf16(Af[c], Bf[t][c], acc, 0, 0, 0);
      const float bv = bs[t * 16 + colf];
#pragma unroll
      for (int r = 0; r < 4; r++) {
        const int row = node0 + quad * 4 + r;
        if (row < n) {
          float o = acc[r] + bv;
          h[(size_t)row * F + t * 16 + colf] = f2h_bits(o);
          ssum[t] += o;
          ssq[t] += o * o;
        }
      }
    }
  }
#pragma unroll
  for (int t = 0; t < FT; t++) {
    atomicAdd(&ls[t * 16 + colf], ssum[t]);
    atomicAdd(&lsq[t * 16 + colf], ssq[t]);
  }
  __syncthreads();
  if (tid < F) {
    atomicAdd(&stats[tid], ls[tid]);
    atomicAdd(&stats[128 + tid], lsq[tid]);
  }
}

// ---------------- Gather (bf16 rows, fp32 accum): m_bf16 = ReLU((1+eps)*y_i + sum y_j + b1) ----

template <int F>
__global__ __launch_bounds__(256) void aggrelu_b(const ushort_t* __restrict__ y,
                                                 const int* __restrict__ row_ptr,
                                                 const int* __restrict__ col,
                                                 const float* __restrict__ epsp,
                                                 const float* __restrict__ b1,
                                                 ushort_t* __restrict__ m, int n) {
  constexpr int LPN = F / 8;      // 16B bf16x8 per lane
  constexpr int NPB = 256 / LPN;  // 32 / 64 / 128 nodes per block
  const int tid = threadIdx.x;
  const int ln = tid / LPN;
  const int fl = tid % LPN;
  const float e1 = 1.0f + epsp[0];
  const float4 b1a = ((const float4*)b1)[fl * 2];
  const float4 b1b = ((const float4*)b1)[fl * 2 + 1];

  const int node = blockIdx.x * NPB + ln;
  if (node >= n) return;
  const uint4* yr = (const uint4*)y;
  const size_t rowi = (size_t)node * LPN + fl;
  const int rs = row_ptr[node], re = row_ptr[node + 1];

  float acc[8];
#pragma unroll
  for (int j = 0; j < 8; j++) acc[j] = 0.f;

  auto addv = [&](uint4 v) {
    acc[0] += __uint_as_float(v.x << 16);
    acc[1] += __uint_as_float(v.x & 0xffff0000u);
    acc[2] += __uint_as_float(v.y << 16);
    acc[3] += __uint_as_float(v.y & 0xffff0000u);
    acc[4] += __uint_as_float(v.z << 16);
    acc[5] += __uint_as_float(v.z & 0xffff0000u);
    acc[6] += __uint_as_float(v.w << 16);
    acc[7] += __uint_as_float(v.w & 0xffff0000u);
  };

  int e = rs;
  for (; e + 8 <= re; e += 8) {
    int c0 = col[e], c1 = col[e + 1], c2 = col[e + 2], c3 = col[e + 3];
    int c4 = col[e + 4], c5 = col[e + 5], c6 = col[e + 6], c7 = col[e + 7];
    uint4 v0 = yr[(size_t)c0 * LPN + fl];
    uint4 v1 = yr[(size_t)c1 * LPN + fl];
    uint4 v2 = yr[(size_t)c2 * LPN + fl];
    uint4 v3 = yr[(size_t)c3 * LPN + fl];
    uint4 v4 = yr[(size_t)c4 * LPN + fl];
    uint4 v5 = yr[(size_t)c5 * LPN + fl];
    uint4 v6 = yr[(size_t)c6 * LPN + fl];
    uint4 v7 = yr[(size_t)c7 * LPN + fl];
    addv(v0);
    addv(v1);
    addv(v2);
    addv(v3);
    addv(v4);
    addv(v5);
    addv(v6);
    addv(v7);
  }
  for (; e + 4 <= re; e += 4) {
    int c0 = col[e], c1 = col[e + 1], c2 = col[e + 2], c3 = col[e + 3];
    uint4 v0 = yr[(size_t)c0 * LPN + fl];
    uint4 v1 = yr[(size_t)c1 * LPN + fl];
    uint4 v2 = yr[(size_t)c2 * LPN + fl];
    uint4 v3 = yr[(size_t)c3 * LPN + fl];
    addv(v0);
    addv(v1);
    addv(v2);
    addv(v3);
  }
  for (; e < re; e++) addv(yr[(size_t)col[e] * LPN + fl]);

  uint4 sv = yr[rowi];
  float r0, r1, r2, r3, r4, r5, r6, r7;
  r0 = fmaxf(fmaf(e1, __uint_as_float(sv.x << 16), acc[0]) + b1a.x, 0.f);
  r1 = fmaxf(fmaf(e1, __uint_as_float(sv.x & 0xffff0000u), acc[1]) + b1a.y, 0.f);
  r2 = fmaxf(fmaf(e1, __uint_as_float(sv.y << 16), acc[2]) + b1a.z, 0.f);
  r3 = fmaxf(fmaf(e1, __uint_as_float(sv.y & 0xffff0000u), acc[3]) + b1a.w, 0.f);
  r4 = fmaxf(fmaf(e1, __uint_as_float(sv.z << 16), acc[4]) + b1b.x, 0.f);
  r5 = fmaxf(fmaf(e1, __uint_as_float(sv.z & 0xffff0000u), acc[5]) + b1b.y, 0.f);
  r6 = fmaxf(fmaf(e1, __uint_as_float(sv.w << 16), acc[6]) + b1b.z, 0.f);
  r7 = fmaxf(fmaf(e1, __uint_as_float(sv.w & 0xffff0000u), acc[7]) + b1b.w, 0.f);
  uint4 o;
  o.x = (unsigned)f2bf(r0) | ((unsigned)f2bf(r1) << 16);
  o.y = (unsigned)f2bf(r2) | ((unsigned)f2bf(r3) << 16);
  o.z = (unsigned)f2bf(r4) | ((unsigned)f2bf(r5) << 16);
  o.w = (unsigned)f2bf(r6) | ((unsigned)f2bf(r7) << 16);
  ((uint4*)m)[rowi] = o;
}

// ---------------- Fused readout: gstart search + BN3-affine + mean + att-c + gated pool ----
// h3 is fp16.

__global__ __launch_bounds__(256) void readout_fused(
    const ushort_t* __restrict__ h3, const int* __restrict__ batch, int n,
    const float* __restrict__ stats, const float* __restrict__ gamma,
    const float* __restrict__ beta, float invN, const float* __restrict__ attW,
    const float* __restrict__ attb, float* __restrict__ hg, int ng) {
  __shared__ float sM[16], oM[16], red[16][17], meanM[16], cM[16];
  __shared__ int seg[2];
  const int tid = threadIdx.x;
  const int g = blockIdx.x;
  const int f = tid & 15, slot = tid >> 4;
  if (tid < 16) {
    float mu = stats[tid] * invN;
    float var = stats[128 + tid] * invN - mu * mu;
    float s = gamma[tid] * rsqrtf(var + 1e-5f);
    sM[tid] = s;
    oM[tid] = beta[tid] - s * mu;
  }
  if (tid >= 32 && tid < 34) {
    const int key = g + (tid - 32);
    int lo = 0, hi = n;
    while (lo < hi) {
      int mid = (lo + hi) >> 1;
      if (batch[mid] < key) lo = mid + 1; else hi = mid;
    }
    seg[tid - 32] = lo;
  }
  __syncthreads();
  const int s0 = seg[0], e0 = seg[1];
  const float sf = sM[f], of = oM[f];

  float acc = 0.f;
  for (int node = s0 + slot; node < e0; node += 16)
    acc += fmaf(h2f_bits(h3[(size_t)node * 16 + f]), sf, of);
  red[slot][f] = acc;
  __syncthreads();
  if (tid < 16) {
    float t = 0.f;
    for (int s = 0; s < 16; s++) t += red[s][tid];
    meanM[tid] = t / fmaxf((float)(e0 - s0), 1.f);
  }
  __syncthreads();
  if (tid < 16) {
    float a = attb[tid];
    for (int k = 0; k < 16; k++) a += meanM[k] * attW[k * 16 + tid];
    cM[tid] = 1.f / (1.f + expf(-a));
  }
  __syncthreads();
  const float cf = cM[f];
  float acc2 = 0.f;
  for (int node = s0 + slot; node < e0; node += 16) {
    float xv = fmaf(h2f_bits(h3[(size_t)node * 16 + f]), sf, of);
    float p = xv * cf;
    for (int m = 8; m >= 1; m >>= 1) p += __shfl_xor(p, m, 16);
    acc2 += xv / (1.f + expf(-p));
  }
  red[slot][f] = acc2;
  __syncthreads();
  if (tid < 16) {
    float t = 0.f;
    for (int s = 0; s < 16; s++) t += red[s][tid];
    hg[g * 16 + tid] = t;
  }
}

// ---------------- EFN + final: 16 lanes per graph, weights + vectors in LDS ----------------

__global__ __launch_bounds__(256) void final3_kernel(
    const float* __restrict__ hgA, const float* __restrict__ hgB, const float* __restrict__ aW1,
    const float* __restrict__ ab1, const float* __restrict__ aW2, const float* __restrict__ ab2,
    const float* __restrict__ mW, const float* __restrict__ mb, const float* __restrict__ fcW1,
    const float* __restrict__ fcb1, const float* __restrict__ fcW2,
    const float* __restrict__ fcb2, float* __restrict__ out, int ng) {
  __shared__ float aW1s[256], aW2s[256], mWs[512], fcW1s[128];
  __shared__ float ab1s[8], ab2s[32], mbs[16], fcb1s[8], fcW2s[8];
  __shared__ float fcb2s;
  __shared__ float hb[16][33], m8b[16][9], encb[16][33], abb[16][17], tb[16][9];
  const int tid = threadIdx.x;
  aW1s[tid] = aW1[tid];
  aW2s[tid] = aW2[tid];
  mWs[tid] = mW[tid];
  mWs[256 + tid] = mW[256 + tid];
  if (tid < 128) fcW1s[tid] = fcW1[tid];
  if (tid < 8) {
    ab1s[tid] = ab1[tid];
    fcb1s[tid] = fcb1[tid];
    fcW2s[tid] = fcW2[tid];
  }
  if (tid < 32) ab2s[tid] = ab2[tid];
  if (tid < 16) mbs[tid] = mb[tid];
  if (tid == 0) fcb2s = fcb2[0];
  __syncthreads();

  const int g = tid >> 4;
  const int l = tid & 15;
  const int gg = blockIdx.x * 16 + g;
  const bool valid = gg < ng;
  const float hiv = valid ? hgA[gg * 16 + l] : 0.f;
  const float hjv = valid ? hgB[gg * 16 + l] : 0.f;
  float res[3];

#pragma unroll
  for (int p = 0; p < 3; p++) {
    float ha = (p == 2) ? hjv : hiv;
    float h2 = (p == 1) ? hiv : hjv;
    hb[g][l] = ha;
    hb[g][16 + l] = h2;
    __syncthreads();
    if (l < 8) {
      float t = ab1s[l];
#pragma unroll
      for (int k = 0; k < 32; k++) t += hb[g][k] * aW1s[k * 8 + l];
      m8b[g][l] = fmaxf(t, 0.f);
    }
    __syncthreads();
    float e0 = ab2s[l], e1 = ab2s[16 + l];
#pragma unroll
    for (int k = 0; k < 8; k++) {
      float mv = m8b[g][k];
      e0 += mv * aW2s[k * 32 + l];
      e1 += mv * aW2s[k * 32 + 16 + l];
    }
    float a0 = tanhf(e0), a1 = tanhf(e1);
    encb[g][l] = fmaf(a0, ha, ha);
    encb[g][16 + l] = fmaf(a1, h2, h2);
    __syncthreads();
    float o = mbs[l];
#pragma unroll
    for (int k = 0; k < 32; k++) o += encb[g][k] * mWs[k * 16 + l];
    res[p] = fmaxf(o, 0.f);
    __syncthreads();
  }

  if (valid) {
    out[ng + gg * 16 + l] = res[0] - res[2];            // h_Ab = AB - BB
    out[ng + ng * 16 + gg * 16 + l] = res[0] - res[1];  // h_aB = AB - AA
  }
  abb[g][l] = res[0];
  __syncthreads();
  if (l < 8) {
    float t = fcb1s[l];
#pragma unroll
    for (int k = 0; k < 16; k++) t += abb[g][k] * fcW1s[k * 8 + l];
    tb[g][l] = fmaxf(t, 0.f);
  }
  __syncthreads();
  if (l == 0 && valid) {
    float sc = fcb2s;
#pragma unroll
    for (int o = 0; o < 8; o++) sc += tb[g][o] * fcW2s[o];
    out[gg] = sc;
  }
}

// ---------------- Launch ----------------

extern "C" void kernel_launch(void* const* d_in, const int* in_sizes, int n_in, void* d_out,
                              int out_size, void* d_ws, size_t ws_size, hipStream_t stream) {
  (void)n_in;
  (void)out_size;
  (void)ws_size;
  const int N = in_sizes[0] / 64;
  const int E = in_sizes[2] / 2;
  const int NG = NGRAPH;
  const int NBK = (N + BKMASK) >> BKSHIFT;
  const int CHUNK = (E + PART_BLOCKS - 1) / PART_BLOCKS;

  char* w = (char*)d_ws;
  auto alloc = [&](size_t bytes) -> void* {
    void* p = (void*)w;
    w += (bytes + 255) & ~(size_t)255;
    return p;
  };
  int* row_ptrA = (int*)alloc((size_t)(N + 1) * 4);
  int* colA = (int*)alloc((size_t)E * 4);
  int* row_ptrB = (int*)alloc((size_t)(N + 1) * 4);
  int* colB = (int*)alloc((size_t)E * 4);
  int* hist = (int*)alloc((size_t)2 * PART_BLOCKS * NBK * 4);
  int* totals = (int*)alloc((size_t)2 * NBK * 4);
  int* boff = (int*)alloc((size_t)2 * (NBK + 1) * 4);
  ushort_t* bufA = (ushort_t*)alloc((size_t)N * 64 * 2);  // 25.6 MB
  ushort_t* bufB = (ushort_t*)alloc((size_t)N * 64 * 2);  // 25.6 MB
  float* stats = (float*)alloc((size_t)2 * 768 * 4);
  float* hgA = (float*)alloc((size_t)NG * 16 * 4);
  float* hgB = (float*)alloc((size_t)NG * 16 * 4);

  // Aliases (disjoint live ranges). y/m bf16, h fp16:
  unsigned* ebufA = (unsigned*)bufA;        // E*4 = 12.8 MB; dead before layer 1
  unsigned* ebufB = ebufA + E;              // E*4 = 12.8 MB
  ushort_t* y1 = bufB;                      // bf16 N*64
  ushort_t* m1 = bufA;                      // bf16 N*64 (over dead ebufs)
  ushort_t* h1 = bufB;                      // fp16 N*64 (y1 dead)
  ushort_t* y2 = bufA;                      // bf16 N*32 (m1 dead)
  ushort_t* m2 = bufA + (size_t)N * 32;     // bf16 N*32
  ushort_t* h2 = bufB;                      // fp16 N*32 (h1 dead)
  ushort_t* y3 = bufA;                      // bf16 N*16 (y2/m2 dead)
  ushort_t* m3 = bufA + (size_t)N * 16;     // bf16 N*16
  ushort_t* h3 = bufB;                      // fp16 N*16 (h2 dead)

  const int* esrc0 = (const int*)d_in[2];
  const int* edst0 = esrc0 + E;
  const int* esrc1 = (const int*)d_in[3];
  const int* edst1 = esrc1 + E;
  const float* attW = (const float*)d_in[27];
  const float* attb = (const float*)d_in[28];
  const float invN = 1.0f / (float)N;

  // ---- bucketed CSR build, BOTH sides batched (blockIdx.y = side) ----
  bucket_hist2<<<dim3(PART_BLOCKS, 2), 1024, 0, stream>>>(edst0, edst1, E, CHUNK, hist, NBK);
  colscan_par2<<<dim3(NBK, 2), PART_BLOCKS, 0, stream>>>(hist, NBK, totals);
  scan_small2<<<2, 1024, 0, stream>>>(totals, NBK, boff);
  partition2<<<dim3(PART_BLOCKS, 2), 1024, 0, stream>>>(esrc0, esrc1, edst0, edst1, E, CHUNK,
                                                        hist, boff, ebufA, ebufB, NBK);
  bucket_csr2<<<dim3(NBK, 2), 1024, 0, stream>>>(ebufA, ebufB, boff, row_ptrA, colA, row_ptrB,
                                                 colB, N, E, NBK);
  hipMemsetAsync(stats, 0, 2 * 768 * 4, stream);

  for (int s = 0; s < 2; s++) {
    const float* x0 = (const float*)d_in[s];
    const int* batch = (const int*)d_in[4 + s];
    const int* row_ptr = s ? row_ptrB : row_ptrA;
    const int* col = s ? colB : colA;
    float* st = stats + s * 768;
    float* hg = s ? hgB : hgA;

    // ---- layer 1 ----
    lin_mfma<64, 64, false, false><<<512, 256, 0, stream>>>(
        x0, (const float*)d_in[7], nullptr, nullptr, nullptr, invN, y1, N);
    aggrelu_b<64><<<(N + 31) / 32, 256, 0, stream>>>(
        y1, row_ptr, col, (const float*)d_in[6], (const float*)d_in[8], m1, N);
    lin2s_mfma<64><<<512, 256, 0, stream>>>(m1, (const float*)d_in[9], (const float*)d_in[10],
                                            h1, st, N);

    // ---- layer 2 ----
    lin_mfma<64, 32, true, true><<<512, 256, 0, stream>>>(
        h1, (const float*)d_in[14], st, (const float*)d_in[11], (const float*)d_in[12], invN,
        y2, N);
    aggrelu_b<32><<<(N + 63) / 64, 256, 0, stream>>>(
        y2, row_ptr, col, (const float*)d_in[13], (const float*)d_in[15], m2, N);
    lin2s_mfma<32><<<512, 256, 0, stream>>>(m2, (const float*)d_in[16], (const float*)d_in[17],
                                            h2, st + 256, N);

    // ---- layer 3 ----
    lin_mfma<32, 16, true, true><<<512, 256, 0, stream>>>(
        h2, (const float*)d_in[21], st + 256, (const float*)d_in[18], (const float*)d_in[19],
        invN, y3, N);
    aggrelu_b<16><<<(N + 127) / 128, 256, 0, stream>>>(
        y3, row_ptr, col, (const float*)d_in[20], (const float*)d_in[22], m3, N);
    lin2s_mfma<16><<<512, 256, 0, stream>>>(m3, (const float*)d_in[23], (const float*)d_in[24],
                                            h3, st + 512, N);

    // ---- fused readout (gstart search inlined; BN3 folded; h3 fp16) ----
    readout_fused<<<NG, 256, 0, stream>>>(h3, batch, N, st + 512, (const float*)d_in[25],
                                          (const float*)d_in[26], invN, attW, attb, hg, NG);
  }

  final3_kernel<<<(NG + 15) / 16, 256, 0, stream>>>(
      hgA, hgB, (const float*)d_in[29], (const float*)d_in[30], (const float*)d_in[31],
      (const float*)d_in[32], (const float*)d_in[33], (const float*)d_in[34],
      (const float*)d_in[35], (const float*)d_in[36], (const float*)d_in[37],
      (const float*)d_in[38], (float*)d_out, NG);
}

// Round 8
// 827.726 us; speedup vs baseline: 1.0818x; 1.0663x over previous
//
#include <hip/hip_runtime.h>
#include <math.h>

#define NGRAPH 1000
#define BKSHIFT 11        // 2048-node buckets
#define BKMASK 2047
#define NBK_MAX 128       // ceil(200000/2048)=98
#define PART_BLOCKS 256
#define LCAP 33792        // LDS col-staging capacity (mean 32768 + 5.7 sigma)

typedef unsigned short ushort_t;
typedef __attribute__((ext_vector_type(8))) short short8;     // 8 bf16 (4 VGPRs)
typedef __attribute__((ext_vector_type(8))) _Float16 half8;   // 8 fp16 (4 VGPRs)
typedef __attribute__((ext_vector_type(4))) float floatx4;    // MFMA accumulator

static __device__ inline ushort_t f2bf(float f) {
  unsigned u = __float_as_uint(f);
  u = (u + 0x7fffu + ((u >> 16) & 1u)) >> 16;  // RNE
  return (ushort_t)u;
}
static __device__ inline ushort_t f2h_bits(float f) {
  return __builtin_bit_cast(ushort_t, (_Float16)f);  // RNE
}
static __device__ inline float h2f_bits(ushort_t u) {
  return (float)__builtin_bit_cast(_Float16, u);
}

// ---------------- Bucketed, atomic-free CSR build (BOTH sides batched) ----------------
// Buckets are 2048 nodes (shift 11). ebuf entries packed to 4B:
// (src << 11) | (dst & 2047)  -- src < 2^18, fits 29 bits.  blockIdx.y = side.

__global__ __launch_bounds__(1024) void bucket_hist2(const int* __restrict__ dst0,
                                                     const int* __restrict__ dst1, int E,
                                                     int chunk, int* __restrict__ hist, int nbk) {
  const int side = blockIdx.y;
  const int* __restrict__ dst = side ? dst1 : dst0;
  __shared__ int lh[NBK_MAX];
  for (int i = threadIdx.x; i < nbk; i += 1024) lh[i] = 0;
  __syncthreads();
  const int e0 = blockIdx.x * chunk;
  const int e1 = min(E, e0 + chunk);
  for (int e = e0 + threadIdx.x; e < e1; e += 1024) atomicAdd(&lh[dst[e] >> BKSHIFT], 1);
  __syncthreads();
  int* row = hist + ((size_t)side * PART_BLOCKS + blockIdx.x) * nbk;
  for (int i = threadIdx.x; i < nbk; i += 1024) row[i] = lh[i];
}

// Parallel column scan: one block per (bucket, side), 256 threads = PART_BLOCKS.
__global__ __launch_bounds__(PART_BLOCKS) void colscan_par2(int* __restrict__ hist, int nbk,
                                                            int* __restrict__ totals) {
  __shared__ int s[PART_BLOCKS];
  const int side = blockIdx.y;
  int* __restrict__ hist_s = hist + (size_t)side * PART_BLOCKS * nbk;
  int* __restrict__ totals_s = totals + side * nbk;
  const int b = blockIdx.x;   // bucket
  const int t = threadIdx.x;  // partition block
  s[t] = hist_s[(size_t)t * nbk + b];
  __syncthreads();
  for (int off = 1; off < PART_BLOCKS; off <<= 1) {
    int u = (t >= off) ? s[t - off] : 0;
    __syncthreads();
    s[t] += u;
    __syncthreads();
  }
  const int exc = (t == 0) ? 0 : s[t - 1];
  hist_s[(size_t)t * nbk + b] = exc;
  if (t == PART_BLOCKS - 1) totals_s[b] = s[PART_BLOCKS - 1];
}

__global__ __launch_bounds__(1024) void scan_small2(const int* __restrict__ in, int n,
                                                    int* __restrict__ out) {
  __shared__ int s[2048];
  const int side = blockIdx.x;
  const int* __restrict__ in_s = in + side * n;
  int* __restrict__ out_s = out + side * (n + 1);
  const int t = threadIdx.x;
  s[t] = (t < n) ? in_s[t] : 0;
  s[t + 1024] = (t + 1024 < n) ? in_s[t + 1024] : 0;
  __syncthreads();
  for (int off = 1; off < 2048; off <<= 1) {
    int v0 = (t >= off) ? s[t - off] : 0;
    int v1 = ((t + 1024) >= off) ? s[t + 1024 - off] : 0;
    __syncthreads();
    s[t] += v0;
    s[t + 1024] += v1;
    __syncthreads();
  }
  if (t < n) out_s[t] = (t == 0) ? 0 : s[t - 1];
  const int u = t + 1024;
  if (u < n) out_s[u] = s[u - 1];
  if (t == 0) out_s[n] = s[n - 1];
}

__global__ __launch_bounds__(1024) void partition2(const int* __restrict__ src0,
                                                   const int* __restrict__ src1,
                                                   const int* __restrict__ dst0,
                                                   const int* __restrict__ dst1, int E, int chunk,
                                                   const int* __restrict__ hist,
                                                   const int* __restrict__ boff,
                                                   unsigned* __restrict__ ebufA,
                                                   unsigned* __restrict__ ebufB, int nbk) {
  const int side = blockIdx.y;
  const int* __restrict__ src = side ? src1 : src0;
  const int* __restrict__ dst = side ? dst1 : dst0;
  const int* __restrict__ boff_s = boff + side * (nbk + 1);
  unsigned* __restrict__ ebuf = side ? ebufB : ebufA;
  __shared__ int lbase[NBK_MAX];
  __shared__ int lcur[NBK_MAX];
  const int* row = hist + ((size_t)side * PART_BLOCKS + blockIdx.x) * nbk;
  for (int i = threadIdx.x; i < nbk; i += 1024) {
    lbase[i] = boff_s[i] + row[i];
    lcur[i] = 0;
  }
  __syncthreads();
  const int e0 = blockIdx.x * chunk;
  const int e1 = min(E, e0 + chunk);
  for (int e = e0 + threadIdx.x; e < e1; e += 1024) {
    int d = dst[e];
    int b = d >> BKSHIFT;
    int pos = lbase[b] + atomicAdd(&lcur[b], 1);
    ebuf[pos] = ((unsigned)src[e] << BKSHIFT) | (unsigned)(d & BKMASK);
  }
}

// CSR finalize with LDS-staged scatter: count -> scan -> scatter into LDS lcol
// (LDS atomics, no HBM partial-line thrash) -> coalesced linear col write-out.
__global__ __launch_bounds__(1024) void bucket_csr2(const unsigned* __restrict__ ebufA,
                                                    const unsigned* __restrict__ ebufB,
                                                    const int* __restrict__ boff,
                                                    int* __restrict__ row_ptrA,
                                                    int* __restrict__ colA,
                                                    int* __restrict__ row_ptrB,
                                                    int* __restrict__ colB, int N, int E,
                                                    int nbk) {
  __shared__ int cnt[2048];
  __shared__ int lcol[LCAP];
  const int side = blockIdx.y;
  const unsigned* __restrict__ ebuf = side ? ebufB : ebufA;
  const int* __restrict__ boff_s = boff + side * (nbk + 1);
  int* __restrict__ row_ptr = side ? row_ptrB : row_ptrA;
  int* __restrict__ col = side ? colB : colA;
  const int b = blockIdx.x;
  const int node0 = b << BKSHIFT;
  const int nn = min(2048, N - node0);
  const int es = boff_s[b], ee = boff_s[b + 1];
  const int ne = ee - es;
  const int t = threadIdx.x;
  cnt[t] = 0;
  cnt[t + 1024] = 0;
  __syncthreads();
  for (int e = es + t; e < ee; e += 1024) atomicAdd(&cnt[ebuf[e] & (unsigned)BKMASK], 1);
  __syncthreads();
  // inclusive Hillis-Steele over 2048 counters (2 per thread, read-sync-write)
  for (int off = 1; off < 2048; off <<= 1) {
    int v0 = (t >= off) ? cnt[t - off] : 0;
    int v1 = ((t + 1024) >= off) ? cnt[t + 1024 - off] : 0;
    __syncthreads();
    cnt[t] += v0;
    cnt[t + 1024] += v1;
    __syncthreads();
  }
  // exclusive starts, in-place (cnt becomes the running cursor array)
  const int ex0 = (t == 0) ? 0 : cnt[t - 1];
  const int ex1 = cnt[t + 1023];
  if (t < nn) row_ptr[node0 + t] = es + ex0;
  if (t + 1024 < nn) row_ptr[node0 + t + 1024] = es + ex1;
  __syncthreads();
  cnt[t] = ex0;
  cnt[t + 1024] = ex1;
  __syncthreads();
  if (ne <= LCAP) {
    for (int e = es + t; e < ee; e += 1024) {
      unsigned u = ebuf[e];
      int li = (int)(u & (unsigned)BKMASK);
      int pos = atomicAdd(&cnt[li], 1);
      lcol[pos] = (int)(u >> BKSHIFT);
    }
    __syncthreads();
    for (int i = t; i < ne; i += 1024) col[es + i] = lcol[i];  // coalesced stream-out
  } else {
    // fallback: direct scatter (statistically ~never taken)
    for (int e = es + t; e < ee; e += 1024) {
      unsigned u = ebuf[e];
      int li = (int)(u & (unsigned)BKMASK);
      int pos = es + atomicAdd(&cnt[li], 1);
      col[pos] = (int)(u >> BKSHIFT);
    }
  }
  if (b == 0 && t == 0) row_ptr[N] = E;
}

// ---------------- MFMA linear (f16): y_bf16 = f16(BN-affine(h)) . W_f16 ----------------
// Input either fp32 (layer 1) or fp16 (h from previous layer). BN affine in fp32.
// A layout: A[m=lane&15][k=quad*8+j]; D layout: D[row=quad*4+r][col=lane&15].

template <int FIN, int FOUT, bool HAS_BN, bool IN_HALF>
__global__ __launch_bounds__(256) void lin_mfma(const void* __restrict__ xin,
                                                const float* __restrict__ W,
                                                const float* __restrict__ stats,
                                                const float* __restrict__ gamma,
                                                const float* __restrict__ beta, float invN,
                                                ushort_t* __restrict__ y, int n) {
  constexpr int KC = FIN / 32;   // k-chunks (FIN in {64,32})
  constexpr int FT = FOUT / 16;  // feature tiles
  __shared__ _Float16 Whf[FIN * FOUT];
  __shared__ float scv[FIN], ofv[FIN];
  const int tid = threadIdx.x;
  for (int i = tid; i < FIN * FOUT; i += 256) Whf[i] = (_Float16)W[i];
  for (int i = tid; i < FIN; i += 256) {
    if constexpr (HAS_BN) {
      float mu = stats[i] * invN;
      float var = stats[128 + i] * invN - mu * mu;
      float s = gamma[i] * rsqrtf(var + 1e-5f);
      scv[i] = s;
      ofv[i] = beta[i] - s * mu;
    } else {
      scv[i] = 1.f;
      ofv[i] = 0.f;
    }
  }
  __syncthreads();
  const int lane = tid & 63, wv = tid >> 6;
  const int colf = lane & 15, quad = lane >> 4, kbase = quad * 8;

  half8 Bf[FT][KC];
#pragma unroll
  for (int t = 0; t < FT; t++)
#pragma unroll
    for (int c = 0; c < KC; c++)
#pragma unroll
      for (int j = 0; j < 8; j++)
        Bf[t][c][j] = Whf[(c * 32 + kbase + j) * FOUT + t * 16 + colf];

  const floatx4 zero4 = {0.f, 0.f, 0.f, 0.f};
  const int ntiles = (n + 15) >> 4;
  for (int nt = blockIdx.x * 4 + wv; nt < ntiles; nt += gridDim.x * 4) {
    const int node0 = nt << 4;
    const int anode = node0 + colf;
    half8 Af[KC];
#pragma unroll
    for (int c = 0; c < KC; c++) {
      if (anode < n) {
        const int kk = c * 32 + kbase;
        if constexpr (IN_HALF) {
          const ushort_t* hp = (const ushort_t*)xin + (size_t)anode * FIN + kk;
          half8 hv = *(const half8*)hp;
#pragma unroll
          for (int j = 0; j < 8; j++)
            Af[c][j] = (_Float16)fmaf((float)hv[j], scv[kk + j], ofv[kk + j]);
        } else {
          const float* xp = (const float*)xin + (size_t)anode * FIN + kk;
          float4 xa = *(const float4*)xp;
          float4 xb = *(const float4*)(xp + 4);
          Af[c][0] = (_Float16)fmaf(xa.x, scv[kk + 0], ofv[kk + 0]);
          Af[c][1] = (_Float16)fmaf(xa.y, scv[kk + 1], ofv[kk + 1]);
          Af[c][2] = (_Float16)fmaf(xa.z, scv[kk + 2], ofv[kk + 2]);
          Af[c][3] = (_Float16)fmaf(xa.w, scv[kk + 3], ofv[kk + 3]);
          Af[c][4] = (_Float16)fmaf(xb.x, scv[kk + 4], ofv[kk + 4]);
          Af[c][5] = (_Float16)fmaf(xb.y, scv[kk + 5], ofv[kk + 5]);
          Af[c][6] = (_Float16)fmaf(xb.z, scv[kk + 6], ofv[kk + 6]);
          Af[c][7] = (_Float16)fmaf(xb.w, scv[kk + 7], ofv[kk + 7]);
        }
      } else {
        Af[c] = half8{0, 0, 0, 0, 0, 0, 0, 0};
      }
    }
#pragma unroll
    for (int t = 0; t < FT; t++) {
      floatx4 acc = zero4;
#pragma unroll
      for (int c = 0; c < KC; c++)
        acc = __builtin_amdgcn_mfma_f32_16x16x32_f16(Af[c], Bf[t][c], acc, 0, 0, 0);
#pragma unroll
      for (int r = 0; r < 4; r++) {
        const int row = node0 + quad * 4 + r;
        if (row < n) y[(size_t)row * FOUT + t * 16 + colf] = f2bf(acc[r]);
      }
    }
  }
}

// ---------------- MFMA second linear: h_fp16 = m_bf16 . W2_bf16 + b2 (+ BN stats fp32) -----

template <int F>
__global__ __launch_bounds__(256) void lin2s_mfma(const ushort_t* __restrict__ m,
                                                  const float* __restrict__ W,
                                                  const float* __restrict__ b,
                                                  ushort_t* __restrict__ h,
                                                  float* __restrict__ stats, int n) {
  constexpr int KC = (F + 31) / 32;  // 2,1,1
  constexpr int FT = F / 16;         // 4,2,1
  __shared__ ushort_t Wbf[F * F];
  __shared__ float bs[F], ls[F], lsq[F];
  const int tid = threadIdx.x;
  for (int i = tid; i < F * F; i += 256) Wbf[i] = f2bf(W[i]);
  if (tid < F) {
    bs[tid] = b[tid];
    ls[tid] = 0.f;
    lsq[tid] = 0.f;
  }
  __syncthreads();
  const int lane = tid & 63, wv = tid >> 6;
  const int colf = lane & 15, quad = lane >> 4, kbase = quad * 8;

  short8 Bf[FT][KC];
#pragma unroll
  for (int t = 0; t < FT; t++)
#pragma unroll
    for (int c = 0; c < KC; c++)
#pragma unroll
      for (int j = 0; j < 8; j++) {
        const int k = c * 32 + kbase + j;
        Bf[t][c][j] = (k < F) ? (short)Wbf[k * F + t * 16 + colf] : (short)0;
      }

  const floatx4 zero4 = {0.f, 0.f, 0.f, 0.f};
  float ssum[FT], ssq[FT];
#pragma unroll
  for (int t = 0; t < FT; t++) {
    ssum[t] = 0.f;
    ssq[t] = 0.f;
  }

  const int ntiles = (n + 15) >> 4;
  for (int nt = blockIdx.x * 4 + wv; nt < ntiles; nt += gridDim.x * 4) {
    const int node0 = nt << 4;
    const int anode = node0 + colf;
    short8 Af[KC];
#pragma unroll
    for (int c = 0; c < KC; c++) {
      const int kk = c * 32 + kbase;
      if (anode < n && kk < F)
        Af[c] = *(const short8*)(m + (size_t)anode * F + kk);
      else
        Af[c] = short8{0, 0, 0, 0, 0, 0, 0, 0};
    }
#pragma unroll
    for (int t = 0; t < FT; t++) {
      floatx4 acc = zero4;
#pragma unroll
      for (int c = 0; c < KC; c++)
        acc = __builtin_amdgcn_mfma_f32_16x16x32_bf16(Af[c], Bf[t][c], acc, 0, 0, 0);
      const float bv = bs[t * 16 + colf];
#pragma unroll
      for (int r = 0; r < 4; r++) {
        const int row = node0 + quad * 4 + r;
        if (row < n) {
          float o = acc[r] + bv;
          h[(size_t)row * F + t * 16 + colf] = f2h_bits(o);
          ssum[t] += o;
          ssq[t] += o * o;
        }
      }
    }
  }
#pragma unroll
  for (int t = 0; t < FT; t++) {
    atomicAdd(&ls[t * 16 + colf], ssum[t]);
    atomicAdd(&lsq[t * 16 + colf], ssq[t]);
  }
  __syncthreads();
  if (tid < F) {
    atomicAdd(&stats[tid], ls[tid]);
    atomicAdd(&stats[128 + tid], lsq[tid]);
  }
}

// ---------------- Gather (bf16 rows, fp32 accum): m_bf16 = ReLU((1+eps)*y_i + sum y_j + b1) ----

template <int F>
__global__ __launch_bounds__(256) void aggrelu_b(const ushort_t* __restrict__ y,
                                                 const int* __restrict__ row_ptr,
                                                 const int* __restrict__ col,
                                                 const float* __restrict__ epsp,
                                                 const float* __restrict__ b1,
                                                 ushort_t* __restrict__ m, int n) {
  constexpr int LPN = F / 8;      // 16B bf16x8 per lane
  constexpr int NPB = 256 / LPN;  // 32 / 64 / 128 nodes per block
  const int tid = threadIdx.x;
  const int ln = tid / LPN;
  const int fl = tid % LPN;
  const float e1 = 1.0f + epsp[0];
  const float4 b1a = ((const float4*)b1)[fl * 2];
  const float4 b1b = ((const float4*)b1)[fl * 2 + 1];

  const int node = blockIdx.x * NPB + ln;
  if (node >= n) return;
  const uint4* yr = (const uint4*)y;
  const size_t rowi = (size_t)node * LPN + fl;
  const int rs = row_ptr[node], re = row_ptr[node + 1];

  float acc[8];
#pragma unroll
  for (int j = 0; j < 8; j++) acc[j] = 0.f;

  auto addv = [&](uint4 v) {
    acc[0] += __uint_as_float(v.x << 16);
    acc[1] += __uint_as_float(v.x & 0xffff0000u);
    acc[2] += __uint_as_float(v.y << 16);
    acc[3] += __uint_as_float(v.y & 0xffff0000u);
    acc[4] += __uint_as_float(v.z << 16);
    acc[5] += __uint_as_float(v.z & 0xffff0000u);
    acc[6] += __uint_as_float(v.w << 16);
    acc[7] += __uint_as_float(v.w & 0xffff0000u);
  };

  int e = rs;
  for (; e + 8 <= re; e += 8) {
    int c0 = col[e], c1 = col[e + 1], c2 = col[e + 2], c3 = col[e + 3];
    int c4 = col[e + 4], c5 = col[e + 5], c6 = col[e + 6], c7 = col[e + 7];
    uint4 v0 = yr[(size_t)c0 * LPN + fl];
    uint4 v1 = yr[(size_t)c1 * LPN + fl];
    uint4 v2 = yr[(size_t)c2 * LPN + fl];
    uint4 v3 = yr[(size_t)c3 * LPN + fl];
    uint4 v4 = yr[(size_t)c4 * LPN + fl];
    uint4 v5 = yr[(size_t)c5 * LPN + fl];
    uint4 v6 = yr[(size_t)c6 * LPN + fl];
    uint4 v7 = yr[(size_t)c7 * LPN + fl];
    addv(v0);
    addv(v1);
    addv(v2);
    addv(v3);
    addv(v4);
    addv(v5);
    addv(v6);
    addv(v7);
  }
  for (; e + 4 <= re; e += 4) {
    int c0 = col[e], c1 = col[e + 1], c2 = col[e + 2], c3 = col[e + 3];
    uint4 v0 = yr[(size_t)c0 * LPN + fl];
    uint4 v1 = yr[(size_t)c1 * LPN + fl];
    uint4 v2 = yr[(size_t)c2 * LPN + fl];
    uint4 v3 = yr[(size_t)c3 * LPN + fl];
    addv(v0);
    addv(v1);
    addv(v2);
    addv(v3);
  }
  for (; e < re; e++) addv(yr[(size_t)col[e] * LPN + fl]);

  uint4 sv = yr[rowi];
  float r0, r1, r2, r3, r4, r5, r6, r7;
  r0 = fmaxf(fmaf(e1, __uint_as_float(sv.x << 16), acc[0]) + b1a.x, 0.f);
  r1 = fmaxf(fmaf(e1, __uint_as_float(sv.x & 0xffff0000u), acc[1]) + b1a.y, 0.f);
  r2 = fmaxf(fmaf(e1, __uint_as_float(sv.y << 16), acc[2]) + b1a.z, 0.f);
  r3 = fmaxf(fmaf(e1, __uint_as_float(sv.y & 0xffff0000u), acc[3]) + b1a.w, 0.f);
  r4 = fmaxf(fmaf(e1, __uint_as_float(sv.z << 16), acc[4]) + b1b.x, 0.f);
  r5 = fmaxf(fmaf(e1, __uint_as_float(sv.z & 0xffff0000u), acc[5]) + b1b.y, 0.f);
  r6 = fmaxf(fmaf(e1, __uint_as_float(sv.w << 16), acc[6]) + b1b.z, 0.f);
  r7 = fmaxf(fmaf(e1, __uint_as_float(sv.w & 0xffff0000u), acc[7]) + b1b.w, 0.f);
  uint4 o;
  o.x = (unsigned)f2bf(r0) | ((unsigned)f2bf(r1) << 16);
  o.y = (unsigned)f2bf(r2) | ((unsigned)f2bf(r3) << 16);
  o.z = (unsigned)f2bf(r4) | ((unsigned)f2bf(r5) << 16);
  o.w = (unsigned)f2bf(r6) | ((unsigned)f2bf(r7) << 16);
  ((uint4*)m)[rowi] = o;
}

// ---------------- Fused readout: gstart search + BN3-affine + mean + att-c + gated pool ----
// h3 is fp16.

__global__ __launch_bounds__(256) void readout_fused(
    const ushort_t* __restrict__ h3, const int* __restrict__ batch, int n,
    const float* __restrict__ stats, const float* __restrict__ gamma,
    const float* __restrict__ beta, float invN, const float* __restrict__ attW,
    const float* __restrict__ attb, float* __restrict__ hg, int ng) {
  __shared__ float sM[16], oM[16], red[16][17], meanM[16], cM[16];
  __shared__ int seg[2];
  const int tid = threadIdx.x;
  const int g = blockIdx.x;
  const int f = tid & 15, slot = tid >> 4;
  if (tid < 16) {
    float mu = stats[tid] * invN;
    float var = stats[128 + tid] * invN - mu * mu;
    float s = gamma[tid] * rsqrtf(var + 1e-5f);
    sM[tid] = s;
    oM[tid] = beta[tid] - s * mu;
  }
  if (tid >= 32 && tid < 34) {
    const int key = g + (tid - 32);
    int lo = 0, hi = n;
    while (lo < hi) {
      int mid = (lo + hi) >> 1;
      if (batch[mid] < key) lo = mid + 1; else hi = mid;
    }
    seg[tid - 32] = lo;
  }
  __syncthreads();
  const int s0 = seg[0], e0 = seg[1];
  const float sf = sM[f], of = oM[f];

  float acc = 0.f;
  for (int node = s0 + slot; node < e0; node += 16)
    acc += fmaf(h2f_bits(h3[(size_t)node * 16 + f]), sf, of);
  red[slot][f] = acc;
  __syncthreads();
  if (tid < 16) {
    float t = 0.f;
    for (int s = 0; s < 16; s++) t += red[s][tid];
    meanM[tid] = t / fmaxf((float)(e0 - s0), 1.f);
  }
  __syncthreads();
  if (tid < 16) {
    float a = attb[tid];
    for (int k = 0; k < 16; k++) a += meanM[k] * attW[k * 16 + tid];
    cM[tid] = 1.f / (1.f + expf(-a));
  }
  __syncthreads();
  const float cf = cM[f];
  float acc2 = 0.f;
  for (int node = s0 + slot; node < e0; node += 16) {
    float xv = fmaf(h2f_bits(h3[(size_t)node * 16 + f]), sf, of);
    float p = xv * cf;
    for (int m = 8; m >= 1; m >>= 1) p += __shfl_xor(p, m, 16);
    acc2 += xv / (1.f + expf(-p));
  }
  red[slot][f] = acc2;
  __syncthreads();
  if (tid < 16) {
    float t = 0.f;
    for (int s = 0; s < 16; s++) t += red[s][tid];
    hg[g * 16 + tid] = t;
  }
}

// ---------------- EFN + final: 16 lanes per graph, weights + vectors in LDS ----------------

__global__ __launch_bounds__(256) void final3_kernel(
    const float* __restrict__ hgA, const float* __restrict__ hgB, const float* __restrict__ aW1,
    const float* __restrict__ ab1, const float* __restrict__ aW2, const float* __restrict__ ab2,
    const float* __restrict__ mW, const float* __restrict__ mb, const float* __restrict__ fcW1,
    const float* __restrict__ fcb1, const float* __restrict__ fcW2,
    const float* __restrict__ fcb2, float* __restrict__ out, int ng) {
  __shared__ float aW1s[256], aW2s[256], mWs[512], fcW1s[128];
  __shared__ float ab1s[8], ab2s[32], mbs[16], fcb1s[8], fcW2s[8];
  __shared__ float fcb2s;
  __shared__ float hb[16][33], m8b[16][9], encb[16][33], abb[16][17], tb[16][9];
  const int tid = threadIdx.x;
  aW1s[tid] = aW1[tid];
  aW2s[tid] = aW2[tid];
  mWs[tid] = mW[tid];
  mWs[256 + tid] = mW[256 + tid];
  if (tid < 128) fcW1s[tid] = fcW1[tid];
  if (tid < 8) {
    ab1s[tid] = ab1[tid];
    fcb1s[tid] = fcb1[tid];
    fcW2s[tid] = fcW2[tid];
  }
  if (tid < 32) ab2s[tid] = ab2[tid];
  if (tid < 16) mbs[tid] = mb[tid];
  if (tid == 0) fcb2s = fcb2[0];
  __syncthreads();

  const int g = tid >> 4;
  const int l = tid & 15;
  const int gg = blockIdx.x * 16 + g;
  const bool valid = gg < ng;
  const float hiv = valid ? hgA[gg * 16 + l] : 0.f;
  const float hjv = valid ? hgB[gg * 16 + l] : 0.f;
  float res[3];

#pragma unroll
  for (int p = 0; p < 3; p++) {
    float ha = (p == 2) ? hjv : hiv;
    float h2 = (p == 1) ? hiv : hjv;
    hb[g][l] = ha;
    hb[g][16 + l] = h2;
    __syncthreads();
    if (l < 8) {
      float t = ab1s[l];
#pragma unroll
      for (int k = 0; k < 32; k++) t += hb[g][k] * aW1s[k * 8 + l];
      m8b[g][l] = fmaxf(t, 0.f);
    }
    __syncthreads();
    float e0 = ab2s[l], e1 = ab2s[16 + l];
#pragma unroll
    for (int k = 0; k < 8; k++) {
      float mv = m8b[g][k];
      e0 += mv * aW2s[k * 32 + l];
      e1 += mv * aW2s[k * 32 + 16 + l];
    }
    float a0 = tanhf(e0), a1 = tanhf(e1);
    encb[g][l] = fmaf(a0, ha, ha);
    encb[g][16 + l] = fmaf(a1, h2, h2);
    __syncthreads();
    float o = mbs[l];
#pragma unroll
    for (int k = 0; k < 32; k++) o += encb[g][k] * mWs[k * 16 + l];
    res[p] = fmaxf(o, 0.f);
    __syncthreads();
  }

  if (valid) {
    out[ng + gg * 16 + l] = res[0] - res[2];            // h_Ab = AB - BB
    out[ng + ng * 16 + gg * 16 + l] = res[0] - res[1];  // h_aB = AB - AA
  }
  abb[g][l] = res[0];
  __syncthreads();
  if (l < 8) {
    float t = fcb1s[l];
#pragma unroll
    for (int k = 0; k < 16; k++) t += abb[g][k] * fcW1s[k * 8 + l];
    tb[g][l] = fmaxf(t, 0.f);
  }
  __syncthreads();
  if (l == 0 && valid) {
    float sc = fcb2s;
#pragma unroll
    for (int o = 0; o < 8; o++) sc += tb[g][o] * fcW2s[o];
    out[gg] = sc;
  }
}

// ---------------- Launch ----------------

extern "C" void kernel_launch(void* const* d_in, const int* in_sizes, int n_in, void* d_out,
                              int out_size, void* d_ws, size_t ws_size, hipStream_t stream) {
  (void)n_in;
  (void)out_size;
  (void)ws_size;
  const int N = in_sizes[0] / 64;
  const int E = in_sizes[2] / 2;
  const int NG = NGRAPH;
  const int NBK = (N + BKMASK) >> BKSHIFT;
  const int CHUNK = (E + PART_BLOCKS - 1) / PART_BLOCKS;

  char* w = (char*)d_ws;
  auto alloc = [&](size_t bytes) -> void* {
    void* p = (void*)w;
    w += (bytes + 255) & ~(size_t)255;
    return p;
  };
  int* row_ptrA = (int*)alloc((size_t)(N + 1) * 4);
  int* colA = (int*)alloc((size_t)E * 4);
  int* row_ptrB = (int*)alloc((size_t)(N + 1) * 4);
  int* colB = (int*)alloc((size_t)E * 4);
  int* hist = (int*)alloc((size_t)2 * PART_BLOCKS * NBK * 4);
  int* totals = (int*)alloc((size_t)2 * NBK * 4);
  int* boff = (int*)alloc((size_t)2 * (NBK + 1) * 4);
  ushort_t* bufA = (ushort_t*)alloc((size_t)N * 64 * 2);  // 25.6 MB
  ushort_t* bufB = (ushort_t*)alloc((size_t)N * 64 * 2);  // 25.6 MB
  float* stats = (float*)alloc((size_t)2 * 768 * 4);
  float* hgA = (float*)alloc((size_t)NG * 16 * 4);
  float* hgB = (float*)alloc((size_t)NG * 16 * 4);

  // Aliases (disjoint live ranges). y/m bf16, h fp16:
  unsigned* ebufA = (unsigned*)bufA;        // E*4 = 12.8 MB; dead before layer 1
  unsigned* ebufB = ebufA + E;              // E*4 = 12.8 MB
  ushort_t* y1 = bufB;                      // bf16 N*64
  ushort_t* m1 = bufA;                      // bf16 N*64 (over dead ebufs)
  ushort_t* h1 = bufB;                      // fp16 N*64 (y1 dead)
  ushort_t* y2 = bufA;                      // bf16 N*32 (m1 dead)
  ushort_t* m2 = bufA + (size_t)N * 32;     // bf16 N*32
  ushort_t* h2 = bufB;                      // fp16 N*32 (h1 dead)
  ushort_t* y3 = bufA;                      // bf16 N*16 (y2/m2 dead)
  ushort_t* m3 = bufA + (size_t)N * 16;     // bf16 N*16
  ushort_t* h3 = bufB;                      // fp16 N*16 (h2 dead)

  const int* esrc0 = (const int*)d_in[2];
  const int* edst0 = esrc0 + E;
  const int* esrc1 = (const int*)d_in[3];
  const int* edst1 = esrc1 + E;
  const float* attW = (const float*)d_in[27];
  const float* attb = (const float*)d_in[28];
  const float invN = 1.0f / (float)N;

  // ---- bucketed CSR build, BOTH sides batched (blockIdx.y = side) ----
  bucket_hist2<<<dim3(PART_BLOCKS, 2), 1024, 0, stream>>>(edst0, edst1, E, CHUNK, hist, NBK);
  colscan_par2<<<dim3(NBK, 2), PART_BLOCKS, 0, stream>>>(hist, NBK, totals);
  scan_small2<<<2, 1024, 0, stream>>>(totals, NBK, boff);
  partition2<<<dim3(PART_BLOCKS, 2), 1024, 0, stream>>>(esrc0, esrc1, edst0, edst1, E, CHUNK,
                                                        hist, boff, ebufA, ebufB, NBK);
  bucket_csr2<<<dim3(NBK, 2), 1024, 0, stream>>>(ebufA, ebufB, boff, row_ptrA, colA, row_ptrB,
                                                 colB, N, E, NBK);
  hipMemsetAsync(stats, 0, 2 * 768 * 4, stream);

  for (int s = 0; s < 2; s++) {
    const float* x0 = (const float*)d_in[s];
    const int* batch = (const int*)d_in[4 + s];
    const int* row_ptr = s ? row_ptrB : row_ptrA;
    const int* col = s ? colB : colA;
    float* st = stats + s * 768;
    float* hg = s ? hgB : hgA;

    // ---- layer 1 ----
    lin_mfma<64, 64, false, false><<<512, 256, 0, stream>>>(
        x0, (const float*)d_in[7], nullptr, nullptr, nullptr, invN, y1, N);
    aggrelu_b<64><<<(N + 31) / 32, 256, 0, stream>>>(
        y1, row_ptr, col, (const float*)d_in[6], (const float*)d_in[8], m1, N);
    lin2s_mfma<64><<<512, 256, 0, stream>>>(m1, (const float*)d_in[9], (const float*)d_in[10],
                                            h1, st, N);

    // ---- layer 2 ----
    lin_mfma<64, 32, true, true><<<512, 256, 0, stream>>>(
        h1, (const float*)d_in[14], st, (const float*)d_in[11], (const float*)d_in[12], invN,
        y2, N);
    aggrelu_b<32><<<(N + 63) / 64, 256, 0, stream>>>(
        y2, row_ptr, col, (const float*)d_in[13], (const float*)d_in[15], m2, N);
    lin2s_mfma<32><<<512, 256, 0, stream>>>(m2, (const float*)d_in[16], (const float*)d_in[17],
                                            h2, st + 256, N);

    // ---- layer 3 ----
    lin_mfma<32, 16, true, true><<<512, 256, 0, stream>>>(
        h2, (const float*)d_in[21], st + 256, (const float*)d_in[18], (const float*)d_in[19],
        invN, y3, N);
    aggrelu_b<16><<<(N + 127) / 128, 256, 0, stream>>>(
        y3, row_ptr, col, (const float*)d_in[20], (const float*)d_in[22], m3, N);
    lin2s_mfma<16><<<512, 256, 0, stream>>>(m3, (const float*)d_in[23], (const float*)d_in[24],
                                            h3, st + 512, N);

    // ---- fused readout (gstart search inlined; BN3 folded; h3 fp16) ----
    readout_fused<<<NG, 256, 0, stream>>>(h3, batch, N, st + 512, (const float*)d_in[25],
                                          (const float*)d_in[26], invN, attW, attb, hg, NG);
  }

  final3_kernel<<<(NG + 15) / 16, 256, 0, stream>>>(
      hgA, hgB, (const float*)d_in[29], (const float*)d_in[30], (const float*)d_in[31],
      (const float*)d_in[32], (const float*)d_in[33], (const float*)d_in[34],
      (const float*)d_in[35], (const float*)d_in[36], (const float*)d_in[37],
      (const float*)d_in[38], (float*)d_out, NG);
}

// Round 9
// 737.167 us; speedup vs baseline: 1.2147x; 1.1228x over previous
//
#include <hip/hip_runtime.h>
#include <math.h>

#define NGRAPH 1000
#define BKSHIFT 11        // 2048-node buckets
#define BKMASK 2047
#define NBK_MAX 128       // ceil(200000/2048)=98
#define PART_BLOCKS 256
#define LCAP 33792        // LDS col-staging capacity (mean 32768 + 5.7 sigma)

typedef unsigned short ushort_t;
typedef __attribute__((ext_vector_type(8))) short short8;     // 8 bf16 (4 VGPRs)
typedef __attribute__((ext_vector_type(8))) _Float16 half8;   // 8 fp16 (4 VGPRs)
typedef __attribute__((ext_vector_type(4))) float floatx4;    // MFMA accumulator

static __device__ inline ushort_t f2bf(float f) {
  unsigned u = __float_as_uint(f);
  u = (u + 0x7fffu + ((u >> 16) & 1u)) >> 16;  // RNE
  return (ushort_t)u;
}
static __device__ inline ushort_t f2h_bits(float f) {
  return __builtin_bit_cast(ushort_t, (_Float16)f);  // RNE
}
static __device__ inline float h2f_bits(ushort_t u) {
  return (float)__builtin_bit_cast(_Float16, u);
}

// ---------------- Bucketed, atomic-free CSR build (BOTH sides batched) ----------------

__global__ __launch_bounds__(1024) void bucket_hist2(const int* __restrict__ dst0,
                                                     const int* __restrict__ dst1, int E,
                                                     int chunk, int* __restrict__ hist, int nbk) {
  const int side = blockIdx.y;
  const int* __restrict__ dst = side ? dst1 : dst0;
  __shared__ int lh[NBK_MAX];
  for (int i = threadIdx.x; i < nbk; i += 1024) lh[i] = 0;
  __syncthreads();
  const int e0 = blockIdx.x * chunk;
  const int e1 = min(E, e0 + chunk);
  for (int e = e0 + threadIdx.x; e < e1; e += 1024) atomicAdd(&lh[dst[e] >> BKSHIFT], 1);
  __syncthreads();
  int* row = hist + ((size_t)side * PART_BLOCKS + blockIdx.x) * nbk;
  for (int i = threadIdx.x; i < nbk; i += 1024) row[i] = lh[i];
}

__global__ __launch_bounds__(PART_BLOCKS) void colscan_par2(int* __restrict__ hist, int nbk,
                                                            int* __restrict__ totals) {
  __shared__ int s[PART_BLOCKS];
  const int side = blockIdx.y;
  int* __restrict__ hist_s = hist + (size_t)side * PART_BLOCKS * nbk;
  int* __restrict__ totals_s = totals + side * nbk;
  const int b = blockIdx.x;
  const int t = threadIdx.x;
  s[t] = hist_s[(size_t)t * nbk + b];
  __syncthreads();
  for (int off = 1; off < PART_BLOCKS; off <<= 1) {
    int u = (t >= off) ? s[t - off] : 0;
    __syncthreads();
    s[t] += u;
    __syncthreads();
  }
  const int exc = (t == 0) ? 0 : s[t - 1];
  hist_s[(size_t)t * nbk + b] = exc;
  if (t == PART_BLOCKS - 1) totals_s[b] = s[PART_BLOCKS - 1];
}

__global__ __launch_bounds__(1024) void scan_small2(const int* __restrict__ in, int n,
                                                    int* __restrict__ out) {
  __shared__ int s[2048];
  const int side = blockIdx.x;
  const int* __restrict__ in_s = in + side * n;
  int* __restrict__ out_s = out + side * (n + 1);
  const int t = threadIdx.x;
  s[t] = (t < n) ? in_s[t] : 0;
  s[t + 1024] = (t + 1024 < n) ? in_s[t + 1024] : 0;
  __syncthreads();
  for (int off = 1; off < 2048; off <<= 1) {
    int v0 = (t >= off) ? s[t - off] : 0;
    int v1 = ((t + 1024) >= off) ? s[t + 1024 - off] : 0;
    __syncthreads();
    s[t] += v0;
    s[t + 1024] += v1;
    __syncthreads();
  }
  if (t < n) out_s[t] = (t == 0) ? 0 : s[t - 1];
  const int u = t + 1024;
  if (u < n) out_s[u] = s[u - 1];
  if (t == 0) out_s[n] = s[n - 1];
}

__global__ __launch_bounds__(1024) void partition2(const int* __restrict__ src0,
                                                   const int* __restrict__ src1,
                                                   const int* __restrict__ dst0,
                                                   const int* __restrict__ dst1, int E, int chunk,
                                                   const int* __restrict__ hist,
                                                   const int* __restrict__ boff,
                                                   unsigned* __restrict__ ebufA,
                                                   unsigned* __restrict__ ebufB, int nbk) {
  const int side = blockIdx.y;
  const int* __restrict__ src = side ? src1 : src0;
  const int* __restrict__ dst = side ? dst1 : dst0;
  const int* __restrict__ boff_s = boff + side * (nbk + 1);
  unsigned* __restrict__ ebuf = side ? ebufB : ebufA;
  __shared__ int lbase[NBK_MAX];
  __shared__ int lcur[NBK_MAX];
  const int* row = hist + ((size_t)side * PART_BLOCKS + blockIdx.x) * nbk;
  for (int i = threadIdx.x; i < nbk; i += 1024) {
    lbase[i] = boff_s[i] + row[i];
    lcur[i] = 0;
  }
  __syncthreads();
  const int e0 = blockIdx.x * chunk;
  const int e1 = min(E, e0 + chunk);
  for (int e = e0 + threadIdx.x; e < e1; e += 1024) {
    int d = dst[e];
    int b = d >> BKSHIFT;
    int pos = lbase[b] + atomicAdd(&lcur[b], 1);
    ebuf[pos] = ((unsigned)src[e] << BKSHIFT) | (unsigned)(d & BKMASK);
  }
}

// CSR finalize with LDS-staged scatter -> coalesced linear col write-out.
__global__ __launch_bounds__(1024) void bucket_csr2(const unsigned* __restrict__ ebufA,
                                                    const unsigned* __restrict__ ebufB,
                                                    const int* __restrict__ boff,
                                                    int* __restrict__ row_ptrA,
                                                    int* __restrict__ colA,
                                                    int* __restrict__ row_ptrB,
                                                    int* __restrict__ colB, int N, int E,
                                                    int nbk) {
  __shared__ int cnt[2048];
  __shared__ int lcol[LCAP];
  const int side = blockIdx.y;
  const unsigned* __restrict__ ebuf = side ? ebufB : ebufA;
  const int* __restrict__ boff_s = boff + side * (nbk + 1);
  int* __restrict__ row_ptr = side ? row_ptrB : row_ptrA;
  int* __restrict__ col = side ? colB : colA;
  const int b = blockIdx.x;
  const int node0 = b << BKSHIFT;
  const int nn = min(2048, N - node0);
  const int es = boff_s[b], ee = boff_s[b + 1];
  const int ne = ee - es;
  const int t = threadIdx.x;
  cnt[t] = 0;
  cnt[t + 1024] = 0;
  __syncthreads();
  for (int e = es + t; e < ee; e += 1024) atomicAdd(&cnt[ebuf[e] & (unsigned)BKMASK], 1);
  __syncthreads();
  for (int off = 1; off < 2048; off <<= 1) {
    int v0 = (t >= off) ? cnt[t - off] : 0;
    int v1 = ((t + 1024) >= off) ? cnt[t + 1024 - off] : 0;
    __syncthreads();
    cnt[t] += v0;
    cnt[t + 1024] += v1;
    __syncthreads();
  }
  const int ex0 = (t == 0) ? 0 : cnt[t - 1];
  const int ex1 = cnt[t + 1023];
  if (t < nn) row_ptr[node0 + t] = es + ex0;
  if (t + 1024 < nn) row_ptr[node0 + t + 1024] = es + ex1;
  __syncthreads();
  cnt[t] = ex0;
  cnt[t + 1024] = ex1;
  __syncthreads();
  if (ne <= LCAP) {
    for (int e = es + t; e < ee; e += 1024) {
      unsigned u = ebuf[e];
      int li = (int)(u & (unsigned)BKMASK);
      int pos = atomicAdd(&cnt[li], 1);
      lcol[pos] = (int)(u >> BKSHIFT);
    }
    __syncthreads();
    for (int i = t; i < ne; i += 1024) col[es + i] = lcol[i];  // coalesced stream-out
  } else {
    for (int e = es + t; e < ee; e += 1024) {
      unsigned u = ebuf[e];
      int li = (int)(u & (unsigned)BKMASK);
      int pos = es + atomicAdd(&cnt[li], 1);
      col[pos] = (int)(u >> BKSHIFT);
    }
  }
  if (b == 0 && t == 0) row_ptr[N] = E;
}

// ---------------- MFMA linear (f16), both sides batched via blockIdx.y ----------------
// A layout: A[m=lane&15][k=quad*8+j]; D layout: D[row=quad*4+r][col=lane&15].

template <int FIN, int FOUT, bool HAS_BN, bool IN_HALF>
__global__ __launch_bounds__(256) void lin_mfma2(const void* __restrict__ xin0,
                                                 const void* __restrict__ xin1,
                                                 const float* __restrict__ W,
                                                 const float* __restrict__ st0,
                                                 const float* __restrict__ st1,
                                                 const float* __restrict__ gamma,
                                                 const float* __restrict__ beta, float invN,
                                                 ushort_t* __restrict__ y0,
                                                 ushort_t* __restrict__ y1, int n) {
  constexpr int KC = FIN / 32;
  constexpr int FT = FOUT / 16;
  const int side = blockIdx.y;
  const void* __restrict__ xin = side ? xin1 : xin0;
  const float* __restrict__ stats = side ? st1 : st0;
  ushort_t* __restrict__ y = side ? y1 : y0;
  __shared__ _Float16 Whf[FIN * FOUT];
  __shared__ float scv[FIN], ofv[FIN];
  const int tid = threadIdx.x;
  for (int i = tid; i < FIN * FOUT; i += 256) Whf[i] = (_Float16)W[i];
  for (int i = tid; i < FIN; i += 256) {
    if constexpr (HAS_BN) {
      float mu = stats[i] * invN;
      float var = stats[128 + i] * invN - mu * mu;
      float s = gamma[i] * rsqrtf(var + 1e-5f);
      scv[i] = s;
      ofv[i] = beta[i] - s * mu;
    } else {
      scv[i] = 1.f;
      ofv[i] = 0.f;
    }
  }
  __syncthreads();
  const int lane = tid & 63, wv = tid >> 6;
  const int colf = lane & 15, quad = lane >> 4, kbase = quad * 8;

  half8 Bf[FT][KC];
#pragma unroll
  for (int t = 0; t < FT; t++)
#pragma unroll
    for (int c = 0; c < KC; c++)
#pragma unroll
      for (int j = 0; j < 8; j++)
        Bf[t][c][j] = Whf[(c * 32 + kbase + j) * FOUT + t * 16 + colf];

  const floatx4 zero4 = {0.f, 0.f, 0.f, 0.f};
  const int ntiles = (n + 15) >> 4;
  for (int nt = blockIdx.x * 4 + wv; nt < ntiles; nt += gridDim.x * 4) {
    const int node0 = nt << 4;
    const int anode = node0 + colf;
    half8 Af[KC];
#pragma unroll
    for (int c = 0; c < KC; c++) {
      if (anode < n) {
        const int kk = c * 32 + kbase;
        if constexpr (IN_HALF) {
          const ushort_t* hp = (const ushort_t*)xin + (size_t)anode * FIN + kk;
          half8 hv = *(const half8*)hp;
#pragma unroll
          for (int j = 0; j < 8; j++)
            Af[c][j] = (_Float16)fmaf((float)hv[j], scv[kk + j], ofv[kk + j]);
        } else {
          const float* xp = (const float*)xin + (size_t)anode * FIN + kk;
          float4 xa = *(const float4*)xp;
          float4 xb = *(const float4*)(xp + 4);
          Af[c][0] = (_Float16)fmaf(xa.x, scv[kk + 0], ofv[kk + 0]);
          Af[c][1] = (_Float16)fmaf(xa.y, scv[kk + 1], ofv[kk + 1]);
          Af[c][2] = (_Float16)fmaf(xa.z, scv[kk + 2], ofv[kk + 2]);
          Af[c][3] = (_Float16)fmaf(xa.w, scv[kk + 3], ofv[kk + 3]);
          Af[c][4] = (_Float16)fmaf(xb.x, scv[kk + 4], ofv[kk + 4]);
          Af[c][5] = (_Float16)fmaf(xb.y, scv[kk + 5], ofv[kk + 5]);
          Af[c][6] = (_Float16)fmaf(xb.z, scv[kk + 6], ofv[kk + 6]);
          Af[c][7] = (_Float16)fmaf(xb.w, scv[kk + 7], ofv[kk + 7]);
        }
      } else {
        Af[c] = half8{0, 0, 0, 0, 0, 0, 0, 0};
      }
    }
#pragma unroll
    for (int t = 0; t < FT; t++) {
      floatx4 acc = zero4;
#pragma unroll
      for (int c = 0; c < KC; c++)
        acc = __builtin_amdgcn_mfma_f32_16x16x32_f16(Af[c], Bf[t][c], acc, 0, 0, 0);
#pragma unroll
      for (int r = 0; r < 4; r++) {
        const int row = node0 + quad * 4 + r;
        if (row < n) y[(size_t)row * FOUT + t * 16 + colf] = f2bf(acc[r]);
      }
    }
  }
}

// ---------------- MFMA second linear, both sides batched ----------------

template <int F>
__global__ __launch_bounds__(256) void lin2s_mfma2(const ushort_t* __restrict__ m0,
                                                   const ushort_t* __restrict__ m1,
                                                   const float* __restrict__ W,
                                                   const float* __restrict__ b,
                                                   ushort_t* __restrict__ h0,
                                                   ushort_t* __restrict__ h1,
                                                   float* __restrict__ st0,
                                                   float* __restrict__ st1, int n) {
  constexpr int KC = (F + 31) / 32;
  constexpr int FT = F / 16;
  const int side = blockIdx.y;
  const ushort_t* __restrict__ m = side ? m1 : m0;
  ushort_t* __restrict__ h = side ? h1 : h0;
  float* __restrict__ stats = side ? st1 : st0;
  __shared__ ushort_t Wbf[F * F];
  __shared__ float bs[F], ls[F], lsq[F];
  const int tid = threadIdx.x;
  for (int i = tid; i < F * F; i += 256) Wbf[i] = f2bf(W[i]);
  if (tid < F) {
    bs[tid] = b[tid];
    ls[tid] = 0.f;
    lsq[tid] = 0.f;
  }
  __syncthreads();
  const int lane = tid & 63, wv = tid >> 6;
  const int colf = lane & 15, quad = lane >> 4, kbase = quad * 8;

  short8 Bf[FT][KC];
#pragma unroll
  for (int t = 0; t < FT; t++)
#pragma unroll
    for (int c = 0; c < KC; c++)
#pragma unroll
      for (int j = 0; j < 8; j++) {
        const int k = c * 32 + kbase + j;
        Bf[t][c][j] = (k < F) ? (short)Wbf[k * F + t * 16 + colf] : (short)0;
      }

  const floatx4 zero4 = {0.f, 0.f, 0.f, 0.f};
  float ssum[FT], ssq[FT];
#pragma unroll
  for (int t = 0; t < FT; t++) {
    ssum[t] = 0.f;
    ssq[t] = 0.f;
  }

  const int ntiles = (n + 15) >> 4;
  for (int nt = blockIdx.x * 4 + wv; nt < ntiles; nt += gridDim.x * 4) {
    const int node0 = nt << 4;
    const int anode = node0 + colf;
    short8 Af[KC];
#pragma unroll
    for (int c = 0; c < KC; c++) {
      const int kk = c * 32 + kbase;
      if (anode < n && kk < F)
        Af[c] = *(const short8*)(m + (size_t)anode * F + kk);
      else
        Af[c] = short8{0, 0, 0, 0, 0, 0, 0, 0};
    }
#pragma unroll
    for (int t = 0; t < FT; t++) {
      floatx4 acc = zero4;
#pragma unroll
      for (int c = 0; c < KC; c++)
        acc = __builtin_amdgcn_mfma_f32_16x16x32_bf16(Af[c], Bf[t][c], acc, 0, 0, 0);
      const float bv = bs[t * 16 + colf];
#pragma unroll
      for (int r = 0; r < 4; r++) {
        const int row = node0 + quad * 4 + r;
        if (row < n) {
          float o = acc[r] + bv;
          h[(size_t)row * F + t * 16 + colf] = f2h_bits(o);
          ssum[t] += o;
          ssq[t] += o * o;
        }
      }
    }
  }
#pragma unroll
  for (int t = 0; t < FT; t++) {
    atomicAdd(&ls[t * 16 + colf], ssum[t]);
    atomicAdd(&lsq[t * 16 + colf], ssq[t]);
  }
  __syncthreads();
  if (tid < F) {
    atomicAdd(&stats[tid], ls[tid]);
    atomicAdd(&stats[128 + tid], lsq[tid]);
  }
}

// ---------------- Gather, both sides batched ----------------

template <int F>
__global__ __launch_bounds__(256) void aggrelu_b2(const ushort_t* __restrict__ ya,
                                                  const ushort_t* __restrict__ yb,
                                                  const int* __restrict__ rp0,
                                                  const int* __restrict__ rp1,
                                                  const int* __restrict__ c0,
                                                  const int* __restrict__ c1,
                                                  const float* __restrict__ epsp,
                                                  const float* __restrict__ b1,
                                                  ushort_t* __restrict__ ma,
                                                  ushort_t* __restrict__ mb, int n) {
  constexpr int LPN = F / 8;
  constexpr int NPB = 256 / LPN;
  const int side = blockIdx.y;
  const ushort_t* __restrict__ y = side ? yb : ya;
  const int* __restrict__ row_ptr = side ? rp1 : rp0;
  const int* __restrict__ col = side ? c1 : c0;
  ushort_t* __restrict__ m = side ? mb : ma;
  const int tid = threadIdx.x;
  const int ln = tid / LPN;
  const int fl = tid % LPN;
  const float e1 = 1.0f + epsp[0];
  const float4 b1a = ((const float4*)b1)[fl * 2];
  const float4 b1b = ((const float4*)b1)[fl * 2 + 1];

  const int node = blockIdx.x * NPB + ln;
  if (node >= n) return;
  const uint4* yr = (const uint4*)y;
  const size_t rowi = (size_t)node * LPN + fl;
  const int rs = row_ptr[node], re = row_ptr[node + 1];

  float acc[8];
#pragma unroll
  for (int j = 0; j < 8; j++) acc[j] = 0.f;

  auto addv = [&](uint4 v) {
    acc[0] += __uint_as_float(v.x << 16);
    acc[1] += __uint_as_float(v.x & 0xffff0000u);
    acc[2] += __uint_as_float(v.y << 16);
    acc[3] += __uint_as_float(v.y & 0xffff0000u);
    acc[4] += __uint_as_float(v.z << 16);
    acc[5] += __uint_as_float(v.z & 0xffff0000u);
    acc[6] += __uint_as_float(v.w << 16);
    acc[7] += __uint_as_float(v.w & 0xffff0000u);
  };

  int e = rs;
  for (; e + 8 <= re; e += 8) {
    int d0 = col[e], d1 = col[e + 1], d2 = col[e + 2], d3 = col[e + 3];
    int d4 = col[e + 4], d5 = col[e + 5], d6 = col[e + 6], d7 = col[e + 7];
    uint4 v0 = yr[(size_t)d0 * LPN + fl];
    uint4 v1 = yr[(size_t)d1 * LPN + fl];
    uint4 v2 = yr[(size_t)d2 * LPN + fl];
    uint4 v3 = yr[(size_t)d3 * LPN + fl];
    uint4 v4 = yr[(size_t)d4 * LPN + fl];
    uint4 v5 = yr[(size_t)d5 * LPN + fl];
    uint4 v6 = yr[(size_t)d6 * LPN + fl];
    uint4 v7 = yr[(size_t)d7 * LPN + fl];
    addv(v0);
    addv(v1);
    addv(v2);
    addv(v3);
    addv(v4);
    addv(v5);
    addv(v6);
    addv(v7);
  }
  for (; e + 4 <= re; e += 4) {
    int d0 = col[e], d1 = col[e + 1], d2 = col[e + 2], d3 = col[e + 3];
    uint4 v0 = yr[(size_t)d0 * LPN + fl];
    uint4 v1 = yr[(size_t)d1 * LPN + fl];
    uint4 v2 = yr[(size_t)d2 * LPN + fl];
    uint4 v3 = yr[(size_t)d3 * LPN + fl];
    addv(v0);
    addv(v1);
    addv(v2);
    addv(v3);
  }
  for (; e < re; e++) addv(yr[(size_t)col[e] * LPN + fl]);

  uint4 sv = yr[rowi];
  float r0, r1, r2, r3, r4, r5, r6, r7;
  r0 = fmaxf(fmaf(e1, __uint_as_float(sv.x << 16), acc[0]) + b1a.x, 0.f);
  r1 = fmaxf(fmaf(e1, __uint_as_float(sv.x & 0xffff0000u), acc[1]) + b1a.y, 0.f);
  r2 = fmaxf(fmaf(e1, __uint_as_float(sv.y << 16), acc[2]) + b1a.z, 0.f);
  r3 = fmaxf(fmaf(e1, __uint_as_float(sv.y & 0xffff0000u), acc[3]) + b1a.w, 0.f);
  r4 = fmaxf(fmaf(e1, __uint_as_float(sv.z << 16), acc[4]) + b1b.x, 0.f);
  r5 = fmaxf(fmaf(e1, __uint_as_float(sv.z & 0xffff0000u), acc[5]) + b1b.y, 0.f);
  r6 = fmaxf(fmaf(e1, __uint_as_float(sv.w << 16), acc[6]) + b1b.z, 0.f);
  r7 = fmaxf(fmaf(e1, __uint_as_float(sv.w & 0xffff0000u), acc[7]) + b1b.w, 0.f);
  uint4 o;
  o.x = (unsigned)f2bf(r0) | ((unsigned)f2bf(r1) << 16);
  o.y = (unsigned)f2bf(r2) | ((unsigned)f2bf(r3) << 16);
  o.z = (unsigned)f2bf(r4) | ((unsigned)f2bf(r5) << 16);
  o.w = (unsigned)f2bf(r6) | ((unsigned)f2bf(r7) << 16);
  ((uint4*)m)[rowi] = o;
}

// ---------------- Fused readout, both sides batched (h3 fp16) ----------------

__global__ __launch_bounds__(256) void readout_fused2(
    const ushort_t* __restrict__ h3a, const ushort_t* __restrict__ h3b,
    const int* __restrict__ batch0, const int* __restrict__ batch1, int n,
    const float* __restrict__ st0, const float* __restrict__ st1,
    const float* __restrict__ gamma, const float* __restrict__ beta, float invN,
    const float* __restrict__ attW, const float* __restrict__ attb,
    float* __restrict__ hgA, float* __restrict__ hgB, int ng) {
  __shared__ float sM[16], oM[16], red[16][17], meanM[16], cM[16];
  __shared__ int seg[2];
  const int side = blockIdx.y;
  const ushort_t* __restrict__ h3 = side ? h3b : h3a;
  const int* __restrict__ batch = side ? batch1 : batch0;
  const float* __restrict__ stats = side ? st1 : st0;
  float* __restrict__ hg = side ? hgB : hgA;
  const int tid = threadIdx.x;
  const int g = blockIdx.x;
  const int f = tid & 15, slot = tid >> 4;
  if (tid < 16) {
    float mu = stats[tid] * invN;
    float var = stats[128 + tid] * invN - mu * mu;
    float s = gamma[tid] * rsqrtf(var + 1e-5f);
    sM[tid] = s;
    oM[tid] = beta[tid] - s * mu;
  }
  if (tid >= 32 && tid < 34) {
    const int key = g + (tid - 32);
    int lo = 0, hi = n;
    while (lo < hi) {
      int mid = (lo + hi) >> 1;
      if (batch[mid] < key) lo = mid + 1; else hi = mid;
    }
    seg[tid - 32] = lo;
  }
  __syncthreads();
  const int s0 = seg[0], e0 = seg[1];
  const float sf = sM[f], of = oM[f];

  float acc = 0.f;
  for (int node = s0 + slot; node < e0; node += 16)
    acc += fmaf(h2f_bits(h3[(size_t)node * 16 + f]), sf, of);
  red[slot][f] = acc;
  __syncthreads();
  if (tid < 16) {
    float t = 0.f;
    for (int s = 0; s < 16; s++) t += red[s][tid];
    meanM[tid] = t / fmaxf((float)(e0 - s0), 1.f);
  }
  __syncthreads();
  if (tid < 16) {
    float a = attb[tid];
    for (int k = 0; k < 16; k++) a += meanM[k] * attW[k * 16 + tid];
    cM[tid] = 1.f / (1.f + expf(-a));
  }
  __syncthreads();
  const float cf = cM[f];
  float acc2 = 0.f;
  for (int node = s0 + slot; node < e0; node += 16) {
    float xv = fmaf(h2f_bits(h3[(size_t)node * 16 + f]), sf, of);
    float p = xv * cf;
    for (int m = 8; m >= 1; m >>= 1) p += __shfl_xor(p, m, 16);
    acc2 += xv / (1.f + expf(-p));
  }
  red[slot][f] = acc2;
  __syncthreads();
  if (tid < 16) {
    float t = 0.f;
    for (int s = 0; s < 16; s++) t += red[s][tid];
    hg[g * 16 + tid] = t;
  }
}

// ---------------- EFN + final ----------------

__global__ __launch_bounds__(256) void final3_kernel(
    const float* __restrict__ hgA, const float* __restrict__ hgB, const float* __restrict__ aW1,
    const float* __restrict__ ab1, const float* __restrict__ aW2, const float* __restrict__ ab2,
    const float* __restrict__ mW, const float* __restrict__ mb, const float* __restrict__ fcW1,
    const float* __restrict__ fcb1, const float* __restrict__ fcW2,
    const float* __restrict__ fcb2, float* __restrict__ out, int ng) {
  __shared__ float aW1s[256], aW2s[256], mWs[512], fcW1s[128];
  __shared__ float ab1s[8], ab2s[32], mbs[16], fcb1s[8], fcW2s[8];
  __shared__ float fcb2s;
  __shared__ float hb[16][33], m8b[16][9], encb[16][33], abb[16][17], tb[16][9];
  const int tid = threadIdx.x;
  aW1s[tid] = aW1[tid];
  aW2s[tid] = aW2[tid];
  mWs[tid] = mW[tid];
  mWs[256 + tid] = mW[256 + tid];
  if (tid < 128) fcW1s[tid] = fcW1[tid];
  if (tid < 8) {
    ab1s[tid] = ab1[tid];
    fcb1s[tid] = fcb1[tid];
    fcW2s[tid] = fcW2[tid];
  }
  if (tid < 32) ab2s[tid] = ab2[tid];
  if (tid < 16) mbs[tid] = mb[tid];
  if (tid == 0) fcb2s = fcb2[0];
  __syncthreads();

  const int g = tid >> 4;
  const int l = tid & 15;
  const int gg = blockIdx.x * 16 + g;
  const bool valid = gg < ng;
  const float hiv = valid ? hgA[gg * 16 + l] : 0.f;
  const float hjv = valid ? hgB[gg * 16 + l] : 0.f;
  float res[3];

#pragma unroll
  for (int p = 0; p < 3; p++) {
    float ha = (p == 2) ? hjv : hiv;
    float h2 = (p == 1) ? hiv : hjv;
    hb[g][l] = ha;
    hb[g][16 + l] = h2;
    __syncthreads();
    if (l < 8) {
      float t = ab1s[l];
#pragma unroll
      for (int k = 0; k < 32; k++) t += hb[g][k] * aW1s[k * 8 + l];
      m8b[g][l] = fmaxf(t, 0.f);
    }
    __syncthreads();
    float e0 = ab2s[l], e1 = ab2s[16 + l];
#pragma unroll
    for (int k = 0; k < 8; k++) {
      float mv = m8b[g][k];
      e0 += mv * aW2s[k * 32 + l];
      e1 += mv * aW2s[k * 32 + 16 + l];
    }
    float a0 = tanhf(e0), a1 = tanhf(e1);
    encb[g][l] = fmaf(a0, ha, ha);
    encb[g][16 + l] = fmaf(a1, h2, h2);
    __syncthreads();
    float o = mbs[l];
#pragma unroll
    for (int k = 0; k < 32; k++) o += encb[g][k] * mWs[k * 16 + l];
    res[p] = fmaxf(o, 0.f);
    __syncthreads();
  }

  if (valid) {
    out[ng + gg * 16 + l] = res[0] - res[2];            // h_Ab = AB - BB
    out[ng + ng * 16 + gg * 16 + l] = res[0] - res[1];  // h_aB = AB - AA
  }
  abb[g][l] = res[0];
  __syncthreads();
  if (l < 8) {
    float t = fcb1s[l];
#pragma unroll
    for (int k = 0; k < 16; k++) t += abb[g][k] * fcW1s[k * 8 + l];
    tb[g][l] = fmaxf(t, 0.f);
  }
  __syncthreads();
  if (l == 0 && valid) {
    float sc = fcb2s;
#pragma unroll
    for (int o = 0; o < 8; o++) sc += tb[g][o] * fcW2s[o];
    out[gg] = sc;
  }
}

// ---------------- Launch ----------------

extern "C" void kernel_launch(void* const* d_in, const int* in_sizes, int n_in, void* d_out,
                              int out_size, void* d_ws, size_t ws_size, hipStream_t stream) {
  (void)n_in;
  (void)out_size;
  (void)ws_size;
  const int N = in_sizes[0] / 64;
  const int E = in_sizes[2] / 2;
  const int NG = NGRAPH;
  const int NBK = (N + BKMASK) >> BKSHIFT;
  const int CHUNK = (E + PART_BLOCKS - 1) / PART_BLOCKS;

  char* w = (char*)d_ws;
  auto alloc = [&](size_t bytes) -> void* {
    void* p = (void*)w;
    w += (bytes + 255) & ~(size_t)255;
    return p;
  };
  int* row_ptrA = (int*)alloc((size_t)(N + 1) * 4);
  int* colA = (int*)alloc((size_t)E * 4);
  int* row_ptrB = (int*)alloc((size_t)(N + 1) * 4);
  int* colB = (int*)alloc((size_t)E * 4);
  int* hist = (int*)alloc((size_t)2 * PART_BLOCKS * NBK * 4);
  int* totals = (int*)alloc((size_t)2 * NBK * 4);
  int* boff = (int*)alloc((size_t)2 * (NBK + 1) * 4);
  // Per-side double buffers (25.6 MB each): sA[side], sB[side]
  ushort_t* sA = (ushort_t*)alloc((size_t)2 * N * 64 * 2);
  ushort_t* sB = (ushort_t*)alloc((size_t)2 * N * 64 * 2);
  float* stats = (float*)alloc((size_t)2 * 768 * 4);
  float* hgA = (float*)alloc((size_t)NG * 16 * 4);
  float* hgB = (float*)alloc((size_t)NG * 16 * 4);

  ushort_t* bA[2] = {sA, sA + (size_t)N * 64};
  ushort_t* bB[2] = {sB, sB + (size_t)N * 64};
  // Per-side aliases (same live-range scheme as before, per side):
  unsigned* ebuf0 = (unsigned*)bA[0];       // E*4 = 12.8 MB <= 25.6 MB
  unsigned* ebuf1 = (unsigned*)bA[1];
  // y1=bB, m1=bA, h1=bB, y2=bA, m2=bA+N*32, h2=bB, y3=bA, m3=bA+N*16, h3=bB

  const int* esrc0 = (const int*)d_in[2];
  const int* edst0 = esrc0 + E;
  const int* esrc1 = (const int*)d_in[3];
  const int* edst1 = esrc1 + E;
  const int* batch0 = (const int*)d_in[4];
  const int* batch1 = (const int*)d_in[5];
  const float* attW = (const float*)d_in[27];
  const float* attb = (const float*)d_in[28];
  const float invN = 1.0f / (float)N;

  // ---- bucketed CSR build, both sides batched ----
  bucket_hist2<<<dim3(PART_BLOCKS, 2), 1024, 0, stream>>>(edst0, edst1, E, CHUNK, hist, NBK);
  colscan_par2<<<dim3(NBK, 2), PART_BLOCKS, 0, stream>>>(hist, NBK, totals);
  scan_small2<<<2, 1024, 0, stream>>>(totals, NBK, boff);
  partition2<<<dim3(PART_BLOCKS, 2), 1024, 0, stream>>>(esrc0, esrc1, edst0, edst1, E, CHUNK,
                                                        hist, boff, ebuf0, ebuf1, NBK);
  bucket_csr2<<<dim3(NBK, 2), 1024, 0, stream>>>(ebuf0, ebuf1, boff, row_ptrA, colA, row_ptrB,
                                                 colB, N, E, NBK);
  hipMemsetAsync(stats, 0, 2 * 768 * 4, stream);

  float* st0 = stats;
  float* st1 = stats + 768;

  // ---- layer 1 (both sides per dispatch) ----
  lin_mfma2<64, 64, false, false><<<dim3(512, 2), 256, 0, stream>>>(
      d_in[0], d_in[1], (const float*)d_in[7], nullptr, nullptr, nullptr, nullptr, invN,
      bB[0], bB[1], N);
  aggrelu_b2<64><<<dim3((N + 31) / 32, 2), 256, 0, stream>>>(
      bB[0], bB[1], row_ptrA, row_ptrB, colA, colB, (const float*)d_in[6],
      (const float*)d_in[8], bA[0], bA[1], N);
  lin2s_mfma2<64><<<dim3(512, 2), 256, 0, stream>>>(bA[0], bA[1], (const float*)d_in[9],
                                                    (const float*)d_in[10], bB[0], bB[1],
                                                    st0, st1, N);

  // ---- layer 2 ----
  lin_mfma2<64, 32, true, true><<<dim3(512, 2), 256, 0, stream>>>(
      bB[0], bB[1], (const float*)d_in[14], st0, st1, (const float*)d_in[11],
      (const float*)d_in[12], invN, bA[0], bA[1], N);
  aggrelu_b2<32><<<dim3((N + 63) / 64, 2), 256, 0, stream>>>(
      bA[0], bA[1], row_ptrA, row_ptrB, colA, colB, (const float*)d_in[13],
      (const float*)d_in[15], bA[0] + (size_t)N * 32, bA[1] + (size_t)N * 32, N);
  lin2s_mfma2<32><<<dim3(512, 2), 256, 0, stream>>>(
      bA[0] + (size_t)N * 32, bA[1] + (size_t)N * 32, (const float*)d_in[16],
      (const float*)d_in[17], bB[0], bB[1], st0 + 256, st1 + 256, N);

  // ---- layer 3 ----
  lin_mfma2<32, 16, true, true><<<dim3(512, 2), 256, 0, stream>>>(
      bB[0], bB[1], (const float*)d_in[21], st0 + 256, st1 + 256, (const float*)d_in[18],
      (const float*)d_in[19], invN, bA[0], bA[1], N);
  aggrelu_b2<16><<<dim3((N + 127) / 128, 2), 256, 0, stream>>>(
      bA[0], bA[1], row_ptrA, row_ptrB, colA, colB, (const float*)d_in[20],
      (const float*)d_in[22], bA[0] + (size_t)N * 16, bA[1] + (size_t)N * 16, N);
  lin2s_mfma2<16><<<dim3(512, 2), 256, 0, stream>>>(
      bA[0] + (size_t)N * 16, bA[1] + (size_t)N * 16, (const float*)d_in[23],
      (const float*)d_in[24], bB[0], bB[1], st0 + 512, st1 + 512, N);

  // ---- fused readout (both sides) ----
  readout_fused2<<<dim3(NG, 2), 256, 0, stream>>>(
      bB[0], bB[1], batch0, batch1, N, st0 + 512, st1 + 512, (const float*)d_in[25],
      (const float*)d_in[26], invN, attW, attb, hgA, hgB, NG);

  final3_kernel<<<(NG + 15) / 16, 256, 0, stream>>>(
      hgA, hgB, (const float*)d_in[29], (const float*)d_in[30], (const float*)d_in[31],
      (const float*)d_in[32], (const float*)d_in[33], (const float*)d_in[34],
      (const float*)d_in[35], (const float*)d_in[36], (const float*)d_in[37],
      (const float*)d_in[38], (float*)d_out, NG);
}